// Round 3
// baseline (951.790 us; speedup 1.0000x reference)
//
#include <hip/hip_runtime.h>
#include <hip/hip_bf16.h>
#include <math.h>

#define N_NODES 50000
#define N_EDGES 1600000
#define IN_FEAT 256
#define HIDDEN 128
#define N_CLASSES 16

#define ECHUNK 8192
#define NCHK 196     // ceil(1600000/8192)
#define NBKT2 391    // ceil(50000/128) buckets of 128 nodes
#define NBINS 512    // padded bin count for scatter
#define BCAP2 4800   // per-bucket capacity: mean 4096, sigma ~64 -> +11 sigma

typedef __attribute__((ext_vector_type(8))) short short8;   // 8 bf16 (A/B frag)
typedef __attribute__((ext_vector_type(4))) float floatx4;  // C/D frag

// bf16 round-to-nearest-even (scalar integer path)
__device__ __forceinline__ unsigned short f2bf(float f) {
    unsigned u = __float_as_uint(f);
    return (unsigned short)((u + 0x7fffu + ((u >> 16) & 1u)) >> 16);
}

// HW packed fp32->bf16x2
__device__ __forceinline__ unsigned pk2bf(float a, float b) {
    __hip_bfloat162 h = __float22bfloat162_rn(make_float2(a, b));
    union { __hip_bfloat162 h; unsigned u; } cv;
    cv.h = h;
    return cv.u;
}

__device__ __forceinline__ float bflo(unsigned u) { return __uint_as_float(u << 16); }
__device__ __forceinline__ float bfhi(unsigned u) { return __uint_as_float(u & 0xffff0000u); }

// ---------------------------------------------------------------------------
// Prep: fixed-capacity buckets of 128 nodes (dst>>7). LDS-count -> 1 global
// atomic per (block,bin) -> local scatter. Blocks 0..127 transpose W1 -> w1t.
// ---------------------------------------------------------------------------
__global__ __launch_bounds__(256) void scatter_edges2(const int* __restrict__ src,
                                                      const int* __restrict__ dst,
                                                      int* __restrict__ cursor,   // [NBINS], zeroed
                                                      unsigned int* __restrict__ sorted,
                                                      const float* __restrict__ W1,
                                                      unsigned short* __restrict__ w1t) {
    __shared__ int hloc[NBINS];
    int t = threadIdx.x;
    hloc[t] = 0;
    hloc[t + 256] = 0;
    if (blockIdx.x < HIDDEN)
        w1t[blockIdx.x * IN_FEAT + t] = f2bf(W1[t * HIDDEN + blockIdx.x]);
    __syncthreads();
    int base = blockIdx.x * ECHUNK;
    int end = min(base + ECHUNK, N_EDGES);
    for (int i = base + t; i < end; i += 256)
        atomicAdd(&hloc[dst[i] >> 7], 1);
    __syncthreads();
    for (int b = t; b < NBINS; b += 256) {
        int cnt = hloc[b];
        int lb = (cnt > 0) ? (b * BCAP2 + atomicAdd(&cursor[b], cnt)) : 0;
        hloc[b] = lb;   // reuse as local cursor (each b owned by one thread)
    }
    __syncthreads();
    for (int i = base + t; i < end; i += 256) {
        int d = dst[i];
        int s = src[i];
        int pos = atomicAdd(&hloc[d >> 7], 1);
        sorted[pos] = ((unsigned)d << 16) | (unsigned)s;
    }
}

// ---------------------------------------------------------------------------
// Per bucket: degree -> dis; ordered scatter (grouped by local dst) into
// csr_src (u16) + csr_dst (u8). Grouping gives same-dst runs that agg1's
// pair-combine exploits.
// ---------------------------------------------------------------------------
__global__ __launch_bounds__(256) void build_csr2(const unsigned int* __restrict__ sorted,
                                                  const int* __restrict__ cursor,
                                                  float* __restrict__ dis,
                                                  unsigned short* __restrict__ csr_src,
                                                  unsigned char* __restrict__ csr_dst) {
    __shared__ int cnt[128];
    __shared__ int cur[128];
    int t = threadIdx.x;
    int bkt = blockIdx.x;
    if (t < 128) cnt[t] = 0;
    __syncthreads();
    int ebase = bkt * BCAP2;
    int eend = ebase + cursor[bkt];
    for (int i = ebase + t; i < eend; i += 256)
        atomicAdd(&cnt[(sorted[i] >> 16) & 127], 1);
    __syncthreads();
    int v = (t < 128) ? cnt[t] : 0;
    if (t < 128) cur[t] = v;
    __syncthreads();
    for (int off = 1; off < 128; off <<= 1) {
        int x = (t < 128 && t >= off) ? cur[t - off] : 0;
        __syncthreads();
        if (t < 128) cur[t] += x;
        __syncthreads();
    }
    if (t < 128) {
        int node = bkt * 128 + t;
        if (node < N_NODES) dis[node] = 1.0f / sqrtf((float)(v + 1));  // +1 self loop
        cur[t] = ebase + cur[t] - v;   // exclusive prefix -> running cursor
    }
    __syncthreads();
    for (int i = ebase + t; i < eend; i += 256) {
        unsigned e = sorted[i];
        unsigned dl = (e >> 16) & 127;
        int pos = atomicAdd(&cur[dl], 1);
        csr_src[pos] = (unsigned short)(e & 0xffffu);
        csr_dst[pos] = (unsigned char)dl;
    }
}

// ---------------------------------------------------------------------------
// GEMM1 via MFMA with LDS-staged A (global_load_lds, width 16).
// Output layout SLICE-MAJOR: g1[slice][node][16 dwords] (3.2 MB planes).
// ---------------------------------------------------------------------------
#define XCH 260   // dwords per 8-row chunk: 8*32 + 4 pad

__global__ __launch_bounds__(256) void gemm1_mfma(const float* __restrict__ x,
                                                  const unsigned short* __restrict__ w1t,
                                                  const float* __restrict__ dis,
                                                  unsigned int* __restrict__ g1) {
    __shared__ float xs[2][8 * XCH];   // 2 x 8320 B
    int tid = threadIdx.x;
    int w = tid >> 6;
    int lane = tid & 63;
    int quad = lane >> 4;
    int c = lane & 15;
    int row_base = blockIdx.x * 64;
    int wrow = (w >> 1) * 32;        // wave's row offset in tile
    int col_base = (w & 1) * 64;

    int st_row = min(row_base + 16 * w + (lane >> 3), N_NODES - 1);       // chunk 2w
    int st_row2 = min(row_base + 16 * w + 8 + (lane >> 3), N_NODES - 1);  // chunk 2w+1
    const float* gp1 = x + (size_t)st_row * IN_FEAT + (lane & 7) * 4;
    const float* gp2 = x + (size_t)st_row2 * IN_FEAT + (lane & 7) * 4;

    floatx4 acc[2][4] = {};
    const unsigned short* bp[4];
#pragma unroll
    for (int nt = 0; nt < 4; ++nt)
        bp[nt] = w1t + (size_t)(col_base + nt * 16 + c) * IN_FEAT + quad * 8;

    int dwoff[2];
#pragma unroll
    for (int rt = 0; rt < 2; ++rt) {
        int rit = wrow + rt * 16 + c;
        dwoff[rt] = (rit >> 3) * XCH + (rit & 7) * 32 + quad * 8;
    }

#define STAGE(buf, k0)                                                                  \
    do {                                                                                \
        __builtin_amdgcn_global_load_lds(                                               \
            (const __attribute__((address_space(1))) void*)(gp1 + (k0)),                \
            (__attribute__((address_space(3))) void*)&xs[buf][(2 * w) * XCH], 16, 0, 0);\
        __builtin_amdgcn_global_load_lds(                                               \
            (const __attribute__((address_space(1))) void*)(gp2 + (k0)),                \
            (__attribute__((address_space(3))) void*)&xs[buf][(2 * w + 1) * XCH], 16, 0, 0);\
    } while (0)

    STAGE(0, 0);
    __syncthreads();

    int buf = 0;
#pragma unroll
    for (int kk = 0; kk < 8; ++kk) {
        if (kk < 7) STAGE(buf ^ 1, (kk + 1) * 32);
        short8 b[4];
#pragma unroll
        for (int nt = 0; nt < 4; ++nt)
            b[nt] = *(const short8*)(bp[nt] + kk * 32);
        short8 a[2];
#pragma unroll
        for (int rt = 0; rt < 2; ++rt) {
            float4 f0 = *(const float4*)&xs[buf][dwoff[rt]];
            float4 f1 = *(const float4*)&xs[buf][dwoff[rt] + 4];
            union { short8 s; unsigned u[4]; } au;
            au.u[0] = pk2bf(f0.x, f0.y);
            au.u[1] = pk2bf(f0.z, f0.w);
            au.u[2] = pk2bf(f1.x, f1.y);
            au.u[3] = pk2bf(f1.z, f1.w);
            a[rt] = au.s;
        }
#pragma unroll
        for (int rt = 0; rt < 2; ++rt)
#pragma unroll
            for (int nt = 0; nt < 4; ++nt)
                acc[rt][nt] = __builtin_amdgcn_mfma_f32_16x16x32_bf16(a[rt], b[nt], acc[rt][nt], 0, 0, 0);
        __syncthreads();
        buf ^= 1;
    }
#undef STAGE

    bool evenlane = (lane & 1) == 0;
#pragma unroll
    for (int rt = 0; rt < 2; ++rt) {
#pragma unroll
        for (int reg = 0; reg < 4; ++reg) {
            int row = row_base + wrow + rt * 16 + quad * 4 + reg;
            float dv = dis[min(row, N_NODES - 1)];
#pragma unroll
            for (int nt = 0; nt < 4; ++nt) {
                float v = acc[rt][nt][reg] * dv;
                float vo = __shfl_xor(v, 1);
                if (evenlane && row < N_NODES) {
                    unsigned pkd = (unsigned)f2bf(v) | ((unsigned)f2bf(vo) << 16);
                    int col = col_base + nt * 16 + c;  // even
                    g1[(size_t)(col >> 5) * (N_NODES * 16) + (size_t)row * 16 + ((col & 31) >> 1)] = pkd;
                }
            }
        }
    }
}

// ---------------------------------------------------------------------------
// Aggregation 1, EDGE-PARALLEL + LDS fp32 accumulators. One block per
// (bucket, slice); slice = blockIdx&3 pins each XCD to one 3.2MB g1 plane.
// acc[128][33] fp32 in LDS (stride 33: conflict-free-ish). 8 lanes/edge,
// each lane gathers 8B (4 feats) and ds_add's. Groups process PAIRS of
// consecutive edges (CSR same-dst runs): combine in regs when d0==d1
// (~97%), halving LDS atomics. 32 disjoint stripes avoid same-address
// atomic pile-ups. Finish: bias+ReLU+GEMM2 partial -> g2p slice plane.
// ---------------------------------------------------------------------------
#define ASTR 33

__global__ __launch_bounds__(256) void agg1_ep(const unsigned int* __restrict__ g1,
                                               const unsigned short* __restrict__ csr_src,
                                               const unsigned char* __restrict__ csr_dst,
                                               const int* __restrict__ cursor,
                                               const float* __restrict__ dis,
                                               const float* __restrict__ b1,
                                               const float* __restrict__ W2,
                                               float* __restrict__ g2p) {
    __shared__ float acc[128 * ASTR];   // 16.9 KB
    __shared__ float w2s[512];          // slice's W2 rows (2 KB)
    __shared__ float b1s[32];
    int tid = threadIdx.x;
    int bi = blockIdx.x;
    int bkt = bi >> 2;
    int slice = bi & 3;
    int nbase = bkt * 128;
    const uint2* plane = (const uint2*)(g1 + (size_t)slice * ((size_t)N_NODES * 16));

    for (int i = tid; i < 512; i += 256) w2s[i] = W2[slice * 512 + i];
    if (tid < 32) b1s[tid] = b1[slice * 32 + tid];
    // init acc rows with self-loop values (g1 already carries dis[src])
    if (tid < 128) {
        int node = nbase + tid;
        if (node < N_NODES) {
            const uint4* p4 = (const uint4*)plane + (size_t)node * 4;
#pragma unroll
            for (int k = 0; k < 4; ++k) {
                uint4 u = p4[k];
                acc[tid * ASTR + 8 * k + 0] = bflo(u.x);
                acc[tid * ASTR + 8 * k + 1] = bfhi(u.x);
                acc[tid * ASTR + 8 * k + 2] = bflo(u.y);
                acc[tid * ASTR + 8 * k + 3] = bfhi(u.y);
                acc[tid * ASTR + 8 * k + 4] = bflo(u.z);
                acc[tid * ASTR + 8 * k + 5] = bfhi(u.z);
                acc[tid * ASTR + 8 * k + 6] = bflo(u.w);
                acc[tid * ASTR + 8 * k + 7] = bfhi(u.w);
            }
        } else {
#pragma unroll
            for (int f = 0; f < 32; ++f) acc[tid * ASTR + f] = 0.f;
        }
    }
    __syncthreads();

    int wave = tid >> 6, lane = tid & 63;
    int g = lane >> 3, m = lane & 7;     // 8 lanes per edge-pair; lane m: feats 4m..4m+3
    int ecnt = cursor[bkt];
    int ebase = bkt * BCAP2;
    int eend = ebase + ecnt;
    int stripe = wave * 8 + g;           // 0..31 disjoint stripes
    int npairs = (ecnt + 1) >> 1;
    int P = (npairs + 31) >> 5;
    int k0 = stripe * P;
    int k1 = min(k0 + P, npairs);

#define GATHER(kk, S1V, D0V, D1V, V1V, U0V, U1V)                          \
    do {                                                                  \
        int e0_ = ebase + 2 * (kk);                                       \
        unsigned sp_ = *(const unsigned*)&csr_src[e0_];                   \
        unsigned short dp_ = *(const unsigned short*)&csr_dst[e0_];       \
        V1V = (e0_ + 1 < eend);                                           \
        int s0_ = (int)(sp_ & 0xffffu);                                   \
        S1V = min((int)(sp_ >> 16), N_NODES - 1);                         \
        D0V = (int)(dp_ & 255u);                                          \
        D1V = V1V ? (int)(dp_ >> 8) : D0V;                                \
        U0V = plane[(size_t)s0_ * 8 + m];                                 \
        U1V = plane[(size_t)S1V * 8 + m];                                 \
    } while (0)

#define CONSUME(D0V, D1V, V1V, U0V, U1V)                                  \
    do {                                                                  \
        float x0 = bflo(U0V.x), x1 = bfhi(U0V.x);                         \
        float x2 = bflo(U0V.y), x3 = bfhi(U0V.y);                         \
        float y0 = bflo(U1V.x), y1 = bfhi(U1V.x);                         \
        float y2 = bflo(U1V.y), y3 = bfhi(U1V.y);                         \
        if (!V1V) { y0 = 0.f; y1 = 0.f; y2 = 0.f; y3 = 0.f; }             \
        float* ap0_ = &acc[D0V * ASTR + 4 * m];                           \
        if (D0V == D1V) {                                                 \
            atomicAdd(ap0_ + 0, x0 + y0); atomicAdd(ap0_ + 1, x1 + y1);   \
            atomicAdd(ap0_ + 2, x2 + y2); atomicAdd(ap0_ + 3, x3 + y3);   \
        } else {                                                          \
            float* ap1_ = &acc[D1V * ASTR + 4 * m];                       \
            atomicAdd(ap0_ + 0, x0); atomicAdd(ap0_ + 1, x1);             \
            atomicAdd(ap0_ + 2, x2); atomicAdd(ap0_ + 3, x3);             \
            atomicAdd(ap1_ + 0, y0); atomicAdd(ap1_ + 1, y1);             \
            atomicAdd(ap1_ + 2, y2); atomicAdd(ap1_ + 3, y3);             \
        }                                                                 \
    } while (0)

    if (k0 < k1) {
        int s1c, d0c, d1c; bool v1c; uint2 U0c, U1c;
        GATHER(k0, s1c, d0c, d1c, v1c, U0c, U1c);
        for (int k = k0 + 1; k < k1; ++k) {
            int s1n, d0n, d1n; bool v1n; uint2 U0n, U1n;
            GATHER(k, s1n, d0n, d1n, v1n, U0n, U1n);
            __builtin_amdgcn_sched_barrier(0);
            CONSUME(d0c, d1c, v1c, U0c, U1c);
            d0c = d0n; d1c = d1n; v1c = v1n; U0c = U0n; U1c = U1n;
        }
        __builtin_amdgcn_sched_barrier(0);
        CONSUME(d0c, d1c, v1c, U0c, U1c);
    }
#undef GATHER
#undef CONSUME
    __syncthreads();

    // finish: 2 threads per node (feat halves), bias+ReLU+GEMM2 partial
    int n = tid >> 1, h = tid & 1;
    int node = nbase + n;
    float p[16];
#pragma unroll
    for (int c = 0; c < 16; ++c) p[c] = 0.f;
    if (node < N_NODES) {
        float dv = dis[node];
        const float* ar = &acc[n * ASTR + 16 * h];
        const float* bb = &b1s[16 * h];
#pragma unroll
        for (int f = 0; f < 16; ++f) {
            float r = fmaxf(fmaf(dv, ar[f], bb[f]), 0.f);
            const float* wr = &w2s[(16 * h + f) * 16];
#pragma unroll
            for (int c = 0; c < 16; ++c) p[c] = fmaf(r, wr[c], p[c]);
        }
    }
#pragma unroll
    for (int c = 0; c < 16; ++c) p[c] += __shfl_xor(p[c], 1);
    if (h == 0 && node < N_NODES) {
        float* gpo = g2p + (size_t)slice * ((size_t)N_NODES * 16) + (size_t)node * 16;
#pragma unroll
        for (int c4 = 0; c4 < 4; ++c4)
            ((float4*)gpo)[c4] = make_float4(p[4 * c4], p[4 * c4 + 1], p[4 * c4 + 2], p[4 * c4 + 3]);
    }
}

// ---------------------------------------------------------------------------
// Combine the 4 per-slice GEMM2 partials + dis scale, in place into plane 0.
// ---------------------------------------------------------------------------
__global__ __launch_bounds__(256) void g2_reduce(float* __restrict__ g2p,
                                                 const float* __restrict__ dis) {
    int i = blockIdx.x * 256 + threadIdx.x;   // one float4 (4 classes)
    if (i >= N_NODES * 4) return;
    const size_t PS = (size_t)N_NODES * 16 / 4;  // plane stride in float4
    const float4* p = (const float4*)g2p;
    float4 a = p[i];
    float4 b = p[i + PS];
    float4 c = p[i + 2 * PS];
    float4 d = p[i + 3 * PS];
    float dv = dis[i >> 2];
    float4 r;
    r.x = dv * ((a.x + b.x) + (c.x + d.x));
    r.y = dv * ((a.y + b.y) + (c.y + d.y));
    r.z = dv * ((a.z + b.z) + (c.z + d.z));
    r.w = dv * ((a.w + b.w) + (c.w + d.w));
    ((float4*)g2p)[i] = r;
}

// ---------------------------------------------------------------------------
// Aggregation 2 + bias + logits + softmax, EDGE-PARALLEL. One block per
// bucket (512 threads). acc[128][17] fp32 in LDS. 4 lanes/edge (float4),
// ds_add; 128 disjoint stripes. Finish: 2 threads/node, softmax via pair shfl.
// g2 (3.2 MB) is L2-resident per XCD by size.
// ---------------------------------------------------------------------------
#define A2STR 17

__global__ __launch_bounds__(512) void agg2_ep(const float4* __restrict__ g2,
                                               const unsigned short* __restrict__ csr_src,
                                               const unsigned char* __restrict__ csr_dst,
                                               const int* __restrict__ cursor,
                                               const float* __restrict__ dis,
                                               const float* __restrict__ b2,
                                               float* __restrict__ out) {
    __shared__ float acc[128 * A2STR];   // 8.7 KB
    int tid = threadIdx.x;
    int bkt = blockIdx.x;
    int nbase = bkt * 128;
    if (tid < 128) {
        int node = nbase + tid;
        if (node < N_NODES) {
#pragma unroll
            for (int k = 0; k < 4; ++k) {
                float4 v = g2[(size_t)node * 4 + k];
                acc[tid * A2STR + 4 * k + 0] = v.x;
                acc[tid * A2STR + 4 * k + 1] = v.y;
                acc[tid * A2STR + 4 * k + 2] = v.z;
                acc[tid * A2STR + 4 * k + 3] = v.w;
            }
        } else {
#pragma unroll
            for (int c = 0; c < 16; ++c) acc[tid * A2STR + c] = 0.f;
        }
    }
    __syncthreads();

    int m = tid & 3;          // lane m: classes 4m..4m+3
    int grp = tid >> 2;       // 0..127 disjoint stripes
    int ecnt = cursor[bkt];
    int ebase = bkt * BCAP2;
    int Q = (ecnt + 127) >> 7;
    int q0 = grp * Q, q1 = min(q0 + Q, ecnt);
    if (q0 < q1) {
        int e = ebase + q0;
        int eE = ebase + q1;
        int sc = csr_src[e];
        int dc = csr_dst[e];
        float4 Uc = g2[(size_t)sc * 4 + m];
        for (++e; e < eE; ++e) {
            int sn = csr_src[e];
            int dn = csr_dst[e];
            float4 Un = g2[(size_t)sn * 4 + m];
            __builtin_amdgcn_sched_barrier(0);
            float* ap = &acc[dc * A2STR + 4 * m];
            atomicAdd(ap + 0, Uc.x); atomicAdd(ap + 1, Uc.y);
            atomicAdd(ap + 2, Uc.z); atomicAdd(ap + 3, Uc.w);
            Uc = Un; dc = dn;
        }
        float* ap = &acc[dc * A2STR + 4 * m];
        atomicAdd(ap + 0, Uc.x); atomicAdd(ap + 1, Uc.y);
        atomicAdd(ap + 2, Uc.z); atomicAdd(ap + 3, Uc.w);
    }
    __syncthreads();

    if (tid < 256) {
        int n = tid >> 1, h = tid & 1;
        int node = nbase + n;
        if (node < N_NODES) {
            float dv = dis[node];
            float lg[8];
            float mx = -3.4e38f;
#pragma unroll
            for (int c = 0; c < 8; ++c) {
                lg[c] = fmaf(dv, acc[n * A2STR + 8 * h + c], b2[8 * h + c]);
                mx = fmaxf(mx, lg[c]);
            }
            mx = fmaxf(mx, __shfl_xor(mx, 1));
            float* po = out + (size_t)node * 16 + 8 * h;
            ((float4*)po)[0] = make_float4(lg[0], lg[1], lg[2], lg[3]);
            ((float4*)po)[1] = make_float4(lg[4], lg[5], lg[6], lg[7]);
            float s = 0.f;
#pragma unroll
            for (int c = 0; c < 8; ++c) { lg[c] = expf(lg[c] - mx); s += lg[c]; }
            s += __shfl_xor(s, 1);
            float inv = 1.0f / s;
            float* qo = out + (size_t)N_NODES * 16 + (size_t)node * 16 + 8 * h;
            ((float4*)qo)[0] = make_float4(lg[0] * inv, lg[1] * inv, lg[2] * inv, lg[3] * inv);
            ((float4*)qo)[1] = make_float4(lg[4] * inv, lg[5] * inv, lg[6] * inv, lg[7] * inv);
        }
    }
}

// ---------------------------------------------------------------------------

extern "C" void kernel_launch(void* const* d_in, const int* in_sizes, int n_in,
                              void* d_out, int out_size, void* d_ws, size_t ws_size,
                              hipStream_t stream) {
    const float* x  = (const float*)d_in[0];
    const int*   ei = (const int*)d_in[1];
    const float* W1 = (const float*)d_in[2];
    const float* b1 = (const float*)d_in[3];
    const float* W2 = (const float*)d_in[4];
    const float* b2 = (const float*)d_in[5];
    float* out = (float*)d_out;

    char* ws = (char*)d_ws;
    size_t off = 0;
    auto alloc = [&](size_t bytes) -> char* {
        char* p = ws + off;
        off = (off + bytes + 511) & ~(size_t)511;
        return p;
    };
    int*   cursor   = (int*)alloc(NBINS * 4);
    float* dis      = (float*)alloc(N_NODES * 4);
    unsigned short* w1t = (unsigned short*)alloc((size_t)HIDDEN * IN_FEAT * 2);
    unsigned short* csr_src = (unsigned short*)alloc((size_t)NBKT2 * BCAP2 * 2);  // 3.75MB holey
    unsigned char*  csr_dst = (unsigned char*)alloc((size_t)NBKT2 * BCAP2);       // 1.88MB holey
    unsigned int* g1 = (unsigned int*)alloc((size_t)N_NODES * 64 * 4);            // slice-major: 4 x [N][16dw]
    float* g2p      = (float*)alloc(4 * (size_t)N_NODES * N_CLASSES * 4);         // per-slice GEMM2 partials
    // sorted edges (391*4800*4 = 7.5MB) alias g1's slab (12.8MB): dead before gemm1.
    unsigned int* sorted = (unsigned int*)g1;
    (void)ws_size; (void)in_sizes; (void)n_in; (void)out_size;

    const int* src = ei;
    const int* dst = ei + N_EDGES;

    hipMemsetAsync(cursor, 0, NBINS * 4, stream);
    scatter_edges2<<<NCHK, 256, 0, stream>>>(src, dst, cursor, sorted, W1, w1t);
    build_csr2<<<NBKT2, 256, 0, stream>>>(sorted, cursor, dis, csr_src, csr_dst);

    gemm1_mfma<<<(N_NODES + 63) / 64, 256, 0, stream>>>(x, w1t, dis, g1);
    agg1_ep<<<NBKT2 * 4, 256, 0, stream>>>(g1, csr_src, csr_dst, cursor, dis, b1, W2, g2p);
    g2_reduce<<<(N_NODES * 4 + 255) / 256, 256, 0, stream>>>(g2p, dis);
    agg2_ep<<<NBKT2, 512, 0, stream>>>((const float4*)g2p, csr_src, csr_dst, cursor, dis, b2, out);
}

// Round 4
// 239.928 us; speedup vs baseline: 3.9670x; 3.9670x over previous
//
#include <hip/hip_runtime.h>
#include <hip/hip_bf16.h>
#include <math.h>

#define N_NODES 50000
#define N_EDGES 1600000
#define IN_FEAT 256
#define HIDDEN 128
#define N_CLASSES 16

#define ECHUNK 8192
#define NCHK 196    // ceil(1600000/8192)
#define NBKT 196    // ceil(50000/256) buckets of 256 nodes
#define BCAP 10240  // per-bucket capacity: mean 8192, std ~90 -> +23 sigma

typedef __attribute__((ext_vector_type(8))) short short8;   // 8 bf16 (A/B frag)
typedef __attribute__((ext_vector_type(4))) float floatx4;  // C/D frag

// bf16 round-to-nearest-even (scalar integer path)
__device__ __forceinline__ unsigned short f2bf(float f) {
    unsigned u = __float_as_uint(f);
    return (unsigned short)((u + 0x7fffu + ((u >> 16) & 1u)) >> 16);
}

// HW packed fp32->bf16x2
__device__ __forceinline__ unsigned pk2bf(float a, float b) {
    __hip_bfloat162 h = __float22bfloat162_rn(make_float2(a, b));
    union { __hip_bfloat162 h; unsigned u; } cv;
    cv.h = h;
    return cv.u;
}

__device__ __forceinline__ float bflo(unsigned u) { return __uint_as_float(u << 16); }
__device__ __forceinline__ float bfhi(unsigned u) { return __uint_as_float(u & 0xffff0000u); }

// ---------------------------------------------------------------------------
// Prep: fixed-capacity buckets. scatter: LDS-count -> 1 global atomic per
// (block,bucket) -> local scatter. Blocks 0..127 also transpose W1 -> w1t.
// ---------------------------------------------------------------------------
__global__ __launch_bounds__(256) void scatter_edges2(const int* __restrict__ src,
                                                      const int* __restrict__ dst,
                                                      int* __restrict__ cursor,   // [256], zeroed
                                                      unsigned int* __restrict__ sorted,
                                                      const float* __restrict__ W1,
                                                      unsigned short* __restrict__ w1t) {
    __shared__ int hloc[256];
    int t = threadIdx.x;
    hloc[t] = 0;
    if (blockIdx.x < HIDDEN)
        w1t[blockIdx.x * IN_FEAT + t] = f2bf(W1[t * HIDDEN + blockIdx.x]);
    __syncthreads();
    int base = blockIdx.x * ECHUNK;
    int end = min(base + ECHUNK, N_EDGES);
    for (int i = base + t; i < end; i += 256)
        atomicAdd(&hloc[dst[i] >> 8], 1);
    __syncthreads();
    int cnt = hloc[t];
    int lbase = t * BCAP + atomicAdd(&cursor[t], cnt);  // block's base in bucket t
    __syncthreads();
    hloc[t] = lbase;  // reuse as local cursor
    __syncthreads();
    for (int i = base + t; i < end; i += 256) {
        int d = dst[i];
        int s = src[i];
        int pos = atomicAdd(&hloc[d >> 8], 1);
        sorted[pos] = ((unsigned)d << 16) | (unsigned)s;
    }
}

__global__ __launch_bounds__(256) void build_csr2(const unsigned int* __restrict__ sorted,
                                                  const int* __restrict__ cursor,
                                                  int* __restrict__ rs,
                                                  int* __restrict__ re,
                                                  float* __restrict__ dis,
                                                  unsigned short* __restrict__ csr_src) {
    __shared__ int cnt[256];
    __shared__ int roff[256];
    int t = threadIdx.x;
    int bkt = blockIdx.x;
    int ebase = bkt * BCAP;
    int eend = ebase + cursor[bkt];
    cnt[t] = 0;
    __syncthreads();
    for (int i = ebase + t; i < eend; i += 256)
        atomicAdd(&cnt[(sorted[i] >> 16) & 255], 1);
    __syncthreads();
    int v = cnt[t];
    roff[t] = v;
    __syncthreads();
    for (int off = 1; off < 256; off <<= 1) {
        int x = (t >= off) ? roff[t - off] : 0;
        __syncthreads();
        roff[t] += x;
        __syncthreads();
    }
    int excl = roff[t] - v;
    int node = bkt * 256 + t;
    if (node < N_NODES) {
        rs[node] = ebase + excl;
        re[node] = ebase + excl + v;
        dis[node] = 1.0f / sqrtf((float)(v + 1));  // +1 self loop
    }
    __syncthreads();
    cnt[t] = ebase + excl;  // reuse as cursor
    __syncthreads();
    for (int i = ebase + t; i < eend; i += 256) {
        unsigned e = sorted[i];
        int pos = atomicAdd(&cnt[(e >> 16) & 255], 1);
        csr_src[pos] = (unsigned short)(e & 0xffffu);
    }
}

// ---------------------------------------------------------------------------
// GEMM1 via MFMA with LDS-staged A (global_load_lds, width 16).
// Output layout SLICE-MAJOR: g1[slice][node][16 dwords]; each 32-feature
// slice is a contiguous 3.2 MB plane (fits one XCD's 4 MB L2).
// ---------------------------------------------------------------------------
#define XCH 260   // dwords per 8-row chunk: 8*32 + 4 pad

__global__ __launch_bounds__(256) void gemm1_mfma(const float* __restrict__ x,
                                                  const unsigned short* __restrict__ w1t,
                                                  const float* __restrict__ dis,
                                                  unsigned int* __restrict__ g1) {
    __shared__ float xs[2][8 * XCH];   // 2 x 8320 B
    int tid = threadIdx.x;
    int w = tid >> 6;
    int lane = tid & 63;
    int quad = lane >> 4;
    int c = lane & 15;
    int row_base = blockIdx.x * 64;
    int wrow = (w >> 1) * 32;        // wave's row offset in tile
    int col_base = (w & 1) * 64;

    int st_row = min(row_base + 16 * w + (lane >> 3), N_NODES - 1);       // chunk 2w
    int st_row2 = min(row_base + 16 * w + 8 + (lane >> 3), N_NODES - 1);  // chunk 2w+1
    const float* gp1 = x + (size_t)st_row * IN_FEAT + (lane & 7) * 4;
    const float* gp2 = x + (size_t)st_row2 * IN_FEAT + (lane & 7) * 4;

    floatx4 acc[2][4] = {};
    const unsigned short* bp[4];
#pragma unroll
    for (int nt = 0; nt < 4; ++nt)
        bp[nt] = w1t + (size_t)(col_base + nt * 16 + c) * IN_FEAT + quad * 8;

    int dwoff[2];
#pragma unroll
    for (int rt = 0; rt < 2; ++rt) {
        int rit = wrow + rt * 16 + c;
        dwoff[rt] = (rit >> 3) * XCH + (rit & 7) * 32 + quad * 8;
    }

#define STAGE(buf, k0)                                                                  \
    do {                                                                                \
        __builtin_amdgcn_global_load_lds(                                               \
            (const __attribute__((address_space(1))) void*)(gp1 + (k0)),                \
            (__attribute__((address_space(3))) void*)&xs[buf][(2 * w) * XCH], 16, 0, 0);\
        __builtin_amdgcn_global_load_lds(                                               \
            (const __attribute__((address_space(1))) void*)(gp2 + (k0)),                \
            (__attribute__((address_space(3))) void*)&xs[buf][(2 * w + 1) * XCH], 16, 0, 0);\
    } while (0)

    STAGE(0, 0);
    __syncthreads();

    int buf = 0;
#pragma unroll
    for (int kk = 0; kk < 8; ++kk) {
        if (kk < 7) STAGE(buf ^ 1, (kk + 1) * 32);
        short8 b[4];
#pragma unroll
        for (int nt = 0; nt < 4; ++nt)
            b[nt] = *(const short8*)(bp[nt] + kk * 32);
        short8 a[2];
#pragma unroll
        for (int rt = 0; rt < 2; ++rt) {
            float4 f0 = *(const float4*)&xs[buf][dwoff[rt]];
            float4 f1 = *(const float4*)&xs[buf][dwoff[rt] + 4];
            union { short8 s; unsigned u[4]; } au;
            au.u[0] = pk2bf(f0.x, f0.y);
            au.u[1] = pk2bf(f0.z, f0.w);
            au.u[2] = pk2bf(f1.x, f1.y);
            au.u[3] = pk2bf(f1.z, f1.w);
            a[rt] = au.s;
        }
#pragma unroll
        for (int rt = 0; rt < 2; ++rt)
#pragma unroll
            for (int nt = 0; nt < 4; ++nt)
                acc[rt][nt] = __builtin_amdgcn_mfma_f32_16x16x32_bf16(a[rt], b[nt], acc[rt][nt], 0, 0, 0);
        __syncthreads();   // drains stage vmcnt + protects buf reuse
        buf ^= 1;
    }
#undef STAGE

    // Epilogue: dis scale, pair adjacent cols via shfl, pack bf16x2, store
    // slice-major. C/D layout: col = lane&15, row = quad*4 + reg.
    bool evenlane = (lane & 1) == 0;
#pragma unroll
    for (int rt = 0; rt < 2; ++rt) {
#pragma unroll
        for (int reg = 0; reg < 4; ++reg) {
            int row = row_base + wrow + rt * 16 + quad * 4 + reg;
            float dv = dis[min(row, N_NODES - 1)];
#pragma unroll
            for (int nt = 0; nt < 4; ++nt) {
                float v = acc[rt][nt][reg] * dv;
                float vo = __shfl_xor(v, 1);
                if (evenlane && row < N_NODES) {
                    unsigned pkd = (unsigned)f2bf(v) | ((unsigned)f2bf(vo) << 16);
                    int col = col_base + nt * 16 + c;  // even
                    g1[(size_t)(col >> 5) * (N_NODES * 16) + (size_t)row * 16 + ((col & 31) >> 1)] = pkd;
                }
            }
        }
    }
}

// ---------------------------------------------------------------------------
// Aggregation 1 + bias + ReLU + per-slice GEMM2 partial. Feature-sliced,
// XCD-pinned (blockIdx&7 -> slice plane, 3.2MB, L2-resident per XCD).
// v3: no-shfl index path (lane loads the batch's 4 u16 indices as one
// aligned uint2 and extracts in-register -> ds_bpermute removed from the
// dependent chain) + depth-3 rotating pipeline (A/B/C slots of 4 edges,
// 8-12 gathers outstanding per lane). Peel rs&3 edges for idx alignment.
// ---------------------------------------------------------------------------
__global__ __launch_bounds__(256) void agg1_sliced(const uint4* __restrict__ g1,
                                                   const int* __restrict__ rs,
                                                   const int* __restrict__ re,
                                                   const unsigned short* __restrict__ csr_src,
                                                   const float* __restrict__ dis,
                                                   const float* __restrict__ b1,
                                                   const float* __restrict__ W2,
                                                   float* __restrict__ g2p) {
    __shared__ float w2s[32 * 16];      // this slice's W2 rows (2 KB)
    __shared__ float rbuf[4][16][36];   // per wave/group r vector (32 feats + pad)
    int tid = threadIdx.x;
    int bi = blockIdx.x;
    int bucket = bi >> 4;               // 196
    int xcd = bi & 7;
    int slice = xcd >> 1;               // XCD pair {2s,2s+1} -> slice s
    int quarter = ((bi >> 3) & 1) * 2 + (xcd & 1);

    for (int i = tid; i < 512; i += 256) w2s[i] = W2[slice * 512 + i];
    __syncthreads();

    int wave = tid >> 6, lane = tid & 63;
    int g = lane >> 2, m4 = lane & 3;   // group g owns a node; lane m4 covers feats 8*m4..8*m4+7
    const uint4* plane = g1 + (size_t)slice * (N_NODES * 4);
    float* gp = g2p + (size_t)slice * ((size_t)N_NODES * 16);
    int node = bucket * 256 + quarter * 64 + wave * 16 + g;
    bool alive = (node < N_NODES);

#define ACC8(u) do { a0 += bflo((u).x); a1 += bfhi((u).x); a2 += bflo((u).y); a3 += bfhi((u).y); \
                     a4 += bflo((u).z); a5 += bfhi((u).z); a6 += bflo((u).w); a7 += bfhi((u).w); } while (0)
#define GATH(IV, U0, U1, U2, U3) do {                       \
        int j0_ = (int)((IV).x & 0xffffu);                  \
        int j1_ = (int)((IV).x >> 16);                      \
        int j2_ = (int)((IV).y & 0xffffu);                  \
        int j3_ = (int)((IV).y >> 16);                      \
        U0 = plane[(size_t)j0_ * 4 + m4];                   \
        U1 = plane[(size_t)j1_ * 4 + m4];                   \
        U2 = plane[(size_t)j2_ * 4 + m4];                   \
        U3 = plane[(size_t)j3_ * 4 + m4];                   \
    } while (0)

    if (alive) {
        uint4 su = plane[(size_t)node * 4 + m4];   // self loop (g1 carries dis[src])
        float a0 = bflo(su.x), a1 = bfhi(su.x), a2 = bflo(su.y), a3 = bfhi(su.y);
        float a4 = bflo(su.z), a5 = bfhi(su.z), a6 = bflo(su.w), a7 = bfhi(su.w);
        int e = rs[node], e1v = re[node];
        // peel to 4-edge alignment so uint2 index loads are 8B-aligned
        while ((e & 3) && e < e1v) {
            int j = csr_src[e];
            uint4 u = plane[(size_t)j * 4 + m4];
            ACC8(u);
            ++e;
        }
        int nb = (e1v - e) >> 2;   // full batches of 4
        if (nb >= 3) {
            uint2 I0, I1, I2;
            uint4 A0, A1, A2, A3, B0, B1, B2, B3, C0, C1, C2, C3;
            I0 = *(const uint2*)&csr_src[e];
            GATH(I0, A0, A1, A2, A3);
            I1 = *(const uint2*)&csr_src[e + 4];
            GATH(I1, B0, B1, B2, B3);
            I2 = *(const uint2*)&csr_src[e + 8];
            GATH(I2, C0, C1, C2, C3);
            __builtin_amdgcn_sched_barrier(0);
            int b = 3;
            while (b + 3 <= nb) {
                ACC8(A0); ACC8(A1); ACC8(A2); ACC8(A3);
                I0 = *(const uint2*)&csr_src[e + 4 * b];
                GATH(I0, A0, A1, A2, A3);
                __builtin_amdgcn_sched_barrier(0);
                ACC8(B0); ACC8(B1); ACC8(B2); ACC8(B3);
                I1 = *(const uint2*)&csr_src[e + 4 * b + 4];
                GATH(I1, B0, B1, B2, B3);
                __builtin_amdgcn_sched_barrier(0);
                ACC8(C0); ACC8(C1); ACC8(C2); ACC8(C3);
                I2 = *(const uint2*)&csr_src[e + 4 * b + 8];
                GATH(I2, C0, C1, C2, C3);
                __builtin_amdgcn_sched_barrier(0);
                b += 3;
            }
            int rem = nb - b;   // 0..2 batches beyond the 3 already loaded
            ACC8(A0); ACC8(A1); ACC8(A2); ACC8(A3);
            if (rem >= 1) { I0 = *(const uint2*)&csr_src[e + 4 * b]; GATH(I0, A0, A1, A2, A3); }
            ACC8(B0); ACC8(B1); ACC8(B2); ACC8(B3);
            if (rem >= 2) { I1 = *(const uint2*)&csr_src[e + 4 * b + 4]; GATH(I1, B0, B1, B2, B3); }
            ACC8(C0); ACC8(C1); ACC8(C2); ACC8(C3);
            if (rem >= 1) { ACC8(A0); ACC8(A1); ACC8(A2); ACC8(A3); }
            if (rem >= 2) { ACC8(B0); ACC8(B1); ACC8(B2); ACC8(B3); }
            e += 4 * nb;
        } else {
            for (int bb = 0; bb < nb; ++bb) {
                uint2 Iv = *(const uint2*)&csr_src[e + 4 * bb];
                uint4 U0, U1, U2, U3;
                GATH(Iv, U0, U1, U2, U3);
                ACC8(U0); ACC8(U1); ACC8(U2); ACC8(U3);
            }
            e += 4 * nb;
        }
        while (e < e1v) {   // tail 0..3 edges
            int j = csr_src[e];
            uint4 u = plane[(size_t)j * 4 + m4];
            ACC8(u);
            ++e;
        }

        // bias + ReLU, publish r (lane owns feats 8*m4..8*m4+7)
        float dv = dis[node];
        float4 bb0 = *(const float4*)&b1[slice * 32 + 8 * m4];
        float4 bb1 = *(const float4*)&b1[slice * 32 + 8 * m4 + 4];
        float4 r0, r1;
        r0.x = fmaxf(fmaf(dv, a0, bb0.x), 0.f);
        r0.y = fmaxf(fmaf(dv, a1, bb0.y), 0.f);
        r0.z = fmaxf(fmaf(dv, a2, bb0.z), 0.f);
        r0.w = fmaxf(fmaf(dv, a3, bb0.w), 0.f);
        r1.x = fmaxf(fmaf(dv, a4, bb1.x), 0.f);
        r1.y = fmaxf(fmaf(dv, a5, bb1.y), 0.f);
        r1.z = fmaxf(fmaf(dv, a6, bb1.z), 0.f);
        r1.w = fmaxf(fmaf(dv, a7, bb1.w), 0.f);
        *(float4*)&rbuf[wave][g][8 * m4] = r0;
        *(float4*)&rbuf[wave][g][8 * m4 + 4] = r1;
    }
    __builtin_amdgcn_sched_barrier(0);   // wave-synchronous LDS: keep reads after writes
    if (alive) {
        // GEMM2 partial: lane m4 computes classes 4*m4..4*m4+3 over all 32 feats
        float p0 = 0.f, p1 = 0.f, p2 = 0.f, p3 = 0.f;
#pragma unroll
        for (int fb = 0; fb < 8; ++fb) {
            float4 rv = *(const float4*)&rbuf[wave][g][fb * 4];
            float4 w0 = *(const float4*)&w2s[(fb * 4 + 0) * 16 + 4 * m4];
            float4 w1 = *(const float4*)&w2s[(fb * 4 + 1) * 16 + 4 * m4];
            float4 w2 = *(const float4*)&w2s[(fb * 4 + 2) * 16 + 4 * m4];
            float4 w3 = *(const float4*)&w2s[(fb * 4 + 3) * 16 + 4 * m4];
            p0 = fmaf(rv.x, w0.x, p0); p1 = fmaf(rv.x, w0.y, p1);
            p2 = fmaf(rv.x, w0.z, p2); p3 = fmaf(rv.x, w0.w, p3);
            p0 = fmaf(rv.y, w1.x, p0); p1 = fmaf(rv.y, w1.y, p1);
            p2 = fmaf(rv.y, w1.z, p2); p3 = fmaf(rv.y, w1.w, p3);
            p0 = fmaf(rv.z, w2.x, p0); p1 = fmaf(rv.z, w2.y, p1);
            p2 = fmaf(rv.z, w2.z, p2); p3 = fmaf(rv.z, w2.w, p3);
            p0 = fmaf(rv.w, w3.x, p0); p1 = fmaf(rv.w, w3.y, p1);
            p2 = fmaf(rv.w, w3.z, p2); p3 = fmaf(rv.w, w3.w, p3);
        }
        float4 pv; pv.x = p0; pv.y = p1; pv.z = p2; pv.w = p3;
        *(float4*)&gp[(size_t)node * 16 + 4 * m4] = pv;
    }
#undef GATH
#undef ACC8
}

// ---------------------------------------------------------------------------
// Combine the 4 per-slice GEMM2 partials + dis scale, in place into plane 0.
// ---------------------------------------------------------------------------
__global__ __launch_bounds__(256) void g2_reduce(float* __restrict__ g2p,
                                                 const float* __restrict__ dis) {
    int i = blockIdx.x * 256 + threadIdx.x;   // one float4 (4 classes)
    if (i >= N_NODES * 4) return;
    const size_t PS = (size_t)N_NODES * 16 / 4;  // plane stride in float4
    const float4* p = (const float4*)g2p;
    float4 a = p[i];
    float4 b = p[i + PS];
    float4 c = p[i + 2 * PS];
    float4 d = p[i + 3 * PS];
    float dv = dis[i >> 2];
    float4 r;
    r.x = dv * ((a.x + b.x) + (c.x + d.x));
    r.y = dv * ((a.y + b.y) + (c.y + d.y));
    r.z = dv * ((a.z + b.z) + (c.z + d.z));
    r.w = dv * ((a.w + b.w) + (c.w + d.w));
    ((float4*)g2p)[i] = r;
}

// ---------------------------------------------------------------------------
// Aggregation 2 + bias + logits + softmax. v3: same no-shfl index loads +
// depth-3 rotating pipeline as agg1. g2 (3.2 MB) L2-resident per XCD.
// ---------------------------------------------------------------------------
__global__ __launch_bounds__(256) void agg2_softmax(const float4* __restrict__ g2,
                                                    const int* __restrict__ rs,
                                                    const int* __restrict__ re,
                                                    const unsigned short* __restrict__ csr_src,
                                                    const float* __restrict__ dis,
                                                    const float* __restrict__ b2,
                                                    float* __restrict__ out) {
    int tid = threadIdx.x;
    int wave = tid >> 6, lane = tid & 63;
    int g = lane >> 2, m4 = lane & 3;   // group owns a node; lane m4 covers classes 4*m4..4*m4+3
    int node = blockIdx.x * 64 + wave * 16 + g;
    if (node >= N_NODES) return;

    float4 acc = g2[(size_t)node * 4 + m4];   // self loop

#define ACC4(u) do { acc.x += (u).x; acc.y += (u).y; acc.z += (u).z; acc.w += (u).w; } while (0)
#define GATH4(IV, U0, U1, U2, U3) do {                      \
        int j0_ = (int)((IV).x & 0xffffu);                  \
        int j1_ = (int)((IV).x >> 16);                      \
        int j2_ = (int)((IV).y & 0xffffu);                  \
        int j3_ = (int)((IV).y >> 16);                      \
        U0 = g2[(size_t)j0_ * 4 + m4];                      \
        U1 = g2[(size_t)j1_ * 4 + m4];                      \
        U2 = g2[(size_t)j2_ * 4 + m4];                      \
        U3 = g2[(size_t)j3_ * 4 + m4];                      \
    } while (0)

    int e = rs[node], e1v = re[node];
    while ((e & 3) && e < e1v) {
        int j = csr_src[e];
        float4 u = g2[(size_t)j * 4 + m4];
        ACC4(u);
        ++e;
    }
    int nb = (e1v - e) >> 2;
    if (nb >= 3) {
        uint2 I0, I1, I2;
        float4 A0, A1, A2, A3, B0, B1, B2, B3, C0, C1, C2, C3;
        I0 = *(const uint2*)&csr_src[e];
        GATH4(I0, A0, A1, A2, A3);
        I1 = *(const uint2*)&csr_src[e + 4];
        GATH4(I1, B0, B1, B2, B3);
        I2 = *(const uint2*)&csr_src[e + 8];
        GATH4(I2, C0, C1, C2, C3);
        __builtin_amdgcn_sched_barrier(0);
        int b = 3;
        while (b + 3 <= nb) {
            ACC4(A0); ACC4(A1); ACC4(A2); ACC4(A3);
            I0 = *(const uint2*)&csr_src[e + 4 * b];
            GATH4(I0, A0, A1, A2, A3);
            __builtin_amdgcn_sched_barrier(0);
            ACC4(B0); ACC4(B1); ACC4(B2); ACC4(B3);
            I1 = *(const uint2*)&csr_src[e + 4 * b + 4];
            GATH4(I1, B0, B1, B2, B3);
            __builtin_amdgcn_sched_barrier(0);
            ACC4(C0); ACC4(C1); ACC4(C2); ACC4(C3);
            I2 = *(const uint2*)&csr_src[e + 4 * b + 8];
            GATH4(I2, C0, C1, C2, C3);
            __builtin_amdgcn_sched_barrier(0);
            b += 3;
        }
        int rem = nb - b;
        ACC4(A0); ACC4(A1); ACC4(A2); ACC4(A3);
        if (rem >= 1) { I0 = *(const uint2*)&csr_src[e + 4 * b]; GATH4(I0, A0, A1, A2, A3); }
        ACC4(B0); ACC4(B1); ACC4(B2); ACC4(B3);
        if (rem >= 2) { I1 = *(const uint2*)&csr_src[e + 4 * b + 4]; GATH4(I1, B0, B1, B2, B3); }
        ACC4(C0); ACC4(C1); ACC4(C2); ACC4(C3);
        if (rem >= 1) { ACC4(A0); ACC4(A1); ACC4(A2); ACC4(A3); }
        if (rem >= 2) { ACC4(B0); ACC4(B1); ACC4(B2); ACC4(B3); }
        e += 4 * nb;
    } else {
        for (int bb = 0; bb < nb; ++bb) {
            uint2 Iv = *(const uint2*)&csr_src[e + 4 * bb];
            float4 U0, U1, U2, U3;
            GATH4(Iv, U0, U1, U2, U3);
            ACC4(U0); ACC4(U1); ACC4(U2); ACC4(U3);
        }
        e += 4 * nb;
    }
    while (e < e1v) {
        int j = csr_src[e];
        float4 u = g2[(size_t)j * 4 + m4];
        ACC4(u);
        ++e;
    }
#undef GATH4
#undef ACC4

    float dv = dis[node];
    float4 bb = *(const float4*)&b2[4 * m4];
    float4 lg;
    lg.x = fmaf(dv, acc.x, bb.x);
    lg.y = fmaf(dv, acc.y, bb.y);
    lg.z = fmaf(dv, acc.z, bb.z);
    lg.w = fmaf(dv, acc.w, bb.w);
    ((float4*)out)[(size_t)node * 4 + m4] = lg;

    // softmax over 16 classes = 4 lanes x 4
    float m = fmaxf(fmaxf(lg.x, lg.y), fmaxf(lg.z, lg.w));
    m = fmaxf(m, __shfl_xor(m, 1));
    m = fmaxf(m, __shfl_xor(m, 2));
    float4 ex;
    ex.x = expf(lg.x - m); ex.y = expf(lg.y - m);
    ex.z = expf(lg.z - m); ex.w = expf(lg.w - m);
    float s = (ex.x + ex.y) + (ex.z + ex.w);
    s += __shfl_xor(s, 1);
    s += __shfl_xor(s, 2);
    float inv = 1.0f / s;
    ex.x *= inv; ex.y *= inv; ex.z *= inv; ex.w *= inv;
    ((float4*)out)[(size_t)N_NODES * 4 + (size_t)node * 4 + m4] = ex;
}

// ---------------------------------------------------------------------------

extern "C" void kernel_launch(void* const* d_in, const int* in_sizes, int n_in,
                              void* d_out, int out_size, void* d_ws, size_t ws_size,
                              hipStream_t stream) {
    const float* x  = (const float*)d_in[0];
    const int*   ei = (const int*)d_in[1];
    const float* W1 = (const float*)d_in[2];
    const float* b1 = (const float*)d_in[3];
    const float* W2 = (const float*)d_in[4];
    const float* b2 = (const float*)d_in[5];
    float* out = (float*)d_out;

    char* ws = (char*)d_ws;
    size_t off = 0;
    auto alloc = [&](size_t bytes) -> char* {
        char* p = ws + off;
        off = (off + bytes + 511) & ~(size_t)511;
        return p;
    };
    int*   cursor   = (int*)alloc(256 * 4);
    float* dis      = (float*)alloc(N_NODES * 4);
    int*   rs       = (int*)alloc(N_NODES * 4);
    int*   re       = (int*)alloc(N_NODES * 4);
    unsigned short* w1t = (unsigned short*)alloc((size_t)HIDDEN * IN_FEAT * 2);
    unsigned short* csr_src = (unsigned short*)alloc((size_t)NBKT * BCAP * 2);  // holey
    unsigned int* g1 = (unsigned int*)alloc((size_t)N_NODES * 64 * 4);          // slice-major: 4 x [N][16dw]
    float* g2p      = (float*)alloc(4 * (size_t)N_NODES * N_CLASSES * 4);       // per-slice GEMM2 partials
    // sorted edges (196*10240*4 = 8.0MB) alias g1's slab (12.8MB): dead before gemm1.
    unsigned int* sorted = (unsigned int*)g1;
    (void)ws_size; (void)in_sizes; (void)n_in; (void)out_size;

    const int* src = ei;
    const int* dst = ei + N_EDGES;

    hipMemsetAsync(cursor, 0, 256 * 4, stream);
    scatter_edges2<<<NCHK, 256, 0, stream>>>(src, dst, cursor, sorted, W1, w1t);
    build_csr2<<<NBKT, 256, 0, stream>>>(sorted, cursor, rs, re, dis, csr_src);

    gemm1_mfma<<<(N_NODES + 63) / 64, 256, 0, stream>>>(x, w1t, dis, g1);
    agg1_sliced<<<NBKT * 16, 256, 0, stream>>>((const uint4*)g1, rs, re, csr_src, dis, b1, W2, g2p);
    g2_reduce<<<(N_NODES * 4 + 255) / 256, 256, 0, stream>>>(g2p, dis);
    agg2_softmax<<<N_NODES / 64 + 1, 256, 0, stream>>>((const float4*)g2p, rs, re, csr_src, dis, b2, out);
}

// Round 5
// 228.054 us; speedup vs baseline: 4.1735x; 1.0521x over previous
//
#include <hip/hip_runtime.h>
#include <hip/hip_bf16.h>
#include <math.h>

#define N_NODES 50000
#define N_EDGES 1600000
#define IN_FEAT 256
#define HIDDEN 128
#define N_CLASSES 16

#define ECHUNK 8192
#define NCHK 196    // ceil(1600000/8192)
#define NBKT 196    // ceil(50000/256) buckets of 256 nodes
#define BCAP 10240  // per-bucket capacity: mean 8192, std ~90 -> +23 sigma

typedef __attribute__((ext_vector_type(8))) short short8;   // 8 bf16 (A/B frag)
typedef __attribute__((ext_vector_type(4))) float floatx4;  // C/D frag

// bf16 round-to-nearest-even (scalar integer path)
__device__ __forceinline__ unsigned short f2bf(float f) {
    unsigned u = __float_as_uint(f);
    return (unsigned short)((u + 0x7fffu + ((u >> 16) & 1u)) >> 16);
}

// HW packed fp32->bf16x2
__device__ __forceinline__ unsigned pk2bf(float a, float b) {
    __hip_bfloat162 h = __float22bfloat162_rn(make_float2(a, b));
    union { __hip_bfloat162 h; unsigned u; } cv;
    cv.h = h;
    return cv.u;
}

__device__ __forceinline__ float bflo(unsigned u) { return __uint_as_float(u << 16); }
__device__ __forceinline__ float bfhi(unsigned u) { return __uint_as_float(u & 0xffff0000u); }

// ---------------------------------------------------------------------------
// Prep: fixed-capacity buckets. scatter: LDS-count -> 1 global atomic per
// (block,bucket) -> local scatter. Blocks 0..127 also transpose W1 -> w1t.
// ---------------------------------------------------------------------------
__global__ __launch_bounds__(256) void scatter_edges2(const int* __restrict__ src,
                                                      const int* __restrict__ dst,
                                                      int* __restrict__ cursor,   // [256], zeroed
                                                      unsigned int* __restrict__ sorted,
                                                      const float* __restrict__ W1,
                                                      unsigned short* __restrict__ w1t) {
    __shared__ int hloc[256];
    int t = threadIdx.x;
    hloc[t] = 0;
    if (blockIdx.x < HIDDEN)
        w1t[blockIdx.x * IN_FEAT + t] = f2bf(W1[t * HIDDEN + blockIdx.x]);
    __syncthreads();
    int base = blockIdx.x * ECHUNK;
    int end = min(base + ECHUNK, N_EDGES);
    for (int i = base + t; i < end; i += 256)
        atomicAdd(&hloc[dst[i] >> 8], 1);
    __syncthreads();
    int cnt = hloc[t];
    int lbase = t * BCAP + atomicAdd(&cursor[t], cnt);  // block's base in bucket t
    __syncthreads();
    hloc[t] = lbase;  // reuse as local cursor
    __syncthreads();
    for (int i = base + t; i < end; i += 256) {
        int d = dst[i];
        int s = src[i];
        int pos = atomicAdd(&hloc[d >> 8], 1);
        sorted[pos] = ((unsigned)d << 16) | (unsigned)s;
    }
}

__global__ __launch_bounds__(256) void build_csr2(const unsigned int* __restrict__ sorted,
                                                  const int* __restrict__ cursor,
                                                  int* __restrict__ rs,
                                                  int* __restrict__ re,
                                                  float* __restrict__ dis,
                                                  unsigned short* __restrict__ csr_src) {
    __shared__ int cnt[256];
    __shared__ int roff[256];
    int t = threadIdx.x;
    int bkt = blockIdx.x;
    int ebase = bkt * BCAP;
    int eend = ebase + cursor[bkt];
    cnt[t] = 0;
    __syncthreads();
    for (int i = ebase + t; i < eend; i += 256)
        atomicAdd(&cnt[(sorted[i] >> 16) & 255], 1);
    __syncthreads();
    int v = cnt[t];
    roff[t] = v;
    __syncthreads();
    for (int off = 1; off < 256; off <<= 1) {
        int x = (t >= off) ? roff[t - off] : 0;
        __syncthreads();
        roff[t] += x;
        __syncthreads();
    }
    int excl = roff[t] - v;
    int node = bkt * 256 + t;
    if (node < N_NODES) {
        rs[node] = ebase + excl;
        re[node] = ebase + excl + v;
        dis[node] = 1.0f / sqrtf((float)(v + 1));  // +1 self loop
    }
    __syncthreads();
    cnt[t] = ebase + excl;  // reuse as cursor
    __syncthreads();
    for (int i = ebase + t; i < eend; i += 256) {
        unsigned e = sorted[i];
        int pos = atomicAdd(&cnt[(e >> 16) & 255], 1);
        csr_src[pos] = (unsigned short)(e & 0xffffu);
    }
}

// ---------------------------------------------------------------------------
// GEMM1 via MFMA with LDS-staged A (global_load_lds, width 16).
// Output layout SLICE-MAJOR: g1[slice][node][16 dwords]; each 32-feature
// slice is a contiguous 3.2 MB plane (fits one XCD's 4 MB L2).
// ---------------------------------------------------------------------------
#define XCH 260   // dwords per 8-row chunk: 8*32 + 4 pad

__global__ __launch_bounds__(256) void gemm1_mfma(const float* __restrict__ x,
                                                  const unsigned short* __restrict__ w1t,
                                                  const float* __restrict__ dis,
                                                  unsigned int* __restrict__ g1) {
    __shared__ float xs[2][8 * XCH];   // 2 x 8320 B
    int tid = threadIdx.x;
    int w = tid >> 6;
    int lane = tid & 63;
    int quad = lane >> 4;
    int c = lane & 15;
    int row_base = blockIdx.x * 64;
    int wrow = (w >> 1) * 32;        // wave's row offset in tile
    int col_base = (w & 1) * 64;

    int st_row = min(row_base + 16 * w + (lane >> 3), N_NODES - 1);       // chunk 2w
    int st_row2 = min(row_base + 16 * w + 8 + (lane >> 3), N_NODES - 1);  // chunk 2w+1
    const float* gp1 = x + (size_t)st_row * IN_FEAT + (lane & 7) * 4;
    const float* gp2 = x + (size_t)st_row2 * IN_FEAT + (lane & 7) * 4;

    floatx4 acc[2][4] = {};
    const unsigned short* bp[4];
#pragma unroll
    for (int nt = 0; nt < 4; ++nt)
        bp[nt] = w1t + (size_t)(col_base + nt * 16 + c) * IN_FEAT + quad * 8;

    int dwoff[2];
#pragma unroll
    for (int rt = 0; rt < 2; ++rt) {
        int rit = wrow + rt * 16 + c;
        dwoff[rt] = (rit >> 3) * XCH + (rit & 7) * 32 + quad * 8;
    }

#define STAGE(buf, k0)                                                                  \
    do {                                                                                \
        __builtin_amdgcn_global_load_lds(                                               \
            (const __attribute__((address_space(1))) void*)(gp1 + (k0)),                \
            (__attribute__((address_space(3))) void*)&xs[buf][(2 * w) * XCH], 16, 0, 0);\
        __builtin_amdgcn_global_load_lds(                                               \
            (const __attribute__((address_space(1))) void*)(gp2 + (k0)),                \
            (__attribute__((address_space(3))) void*)&xs[buf][(2 * w + 1) * XCH], 16, 0, 0);\
    } while (0)

    STAGE(0, 0);
    __syncthreads();

    int buf = 0;
#pragma unroll
    for (int kk = 0; kk < 8; ++kk) {
        if (kk < 7) STAGE(buf ^ 1, (kk + 1) * 32);
        short8 b[4];
#pragma unroll
        for (int nt = 0; nt < 4; ++nt)
            b[nt] = *(const short8*)(bp[nt] + kk * 32);
        short8 a[2];
#pragma unroll
        for (int rt = 0; rt < 2; ++rt) {
            float4 f0 = *(const float4*)&xs[buf][dwoff[rt]];
            float4 f1 = *(const float4*)&xs[buf][dwoff[rt] + 4];
            union { short8 s; unsigned u[4]; } au;
            au.u[0] = pk2bf(f0.x, f0.y);
            au.u[1] = pk2bf(f0.z, f0.w);
            au.u[2] = pk2bf(f1.x, f1.y);
            au.u[3] = pk2bf(f1.z, f1.w);
            a[rt] = au.s;
        }
#pragma unroll
        for (int rt = 0; rt < 2; ++rt)
#pragma unroll
            for (int nt = 0; nt < 4; ++nt)
                acc[rt][nt] = __builtin_amdgcn_mfma_f32_16x16x32_bf16(a[rt], b[nt], acc[rt][nt], 0, 0, 0);
        __syncthreads();   // drains stage vmcnt + protects buf reuse
        buf ^= 1;
    }
#undef STAGE

    // Epilogue: dis scale, pair adjacent cols via shfl, pack bf16x2, store
    // slice-major. C/D layout: col = lane&15, row = quad*4 + reg.
    bool evenlane = (lane & 1) == 0;
#pragma unroll
    for (int rt = 0; rt < 2; ++rt) {
#pragma unroll
        for (int reg = 0; reg < 4; ++reg) {
            int row = row_base + wrow + rt * 16 + quad * 4 + reg;
            float dv = dis[min(row, N_NODES - 1)];
#pragma unroll
            for (int nt = 0; nt < 4; ++nt) {
                float v = acc[rt][nt][reg] * dv;
                float vo = __shfl_xor(v, 1);
                if (evenlane && row < N_NODES) {
                    unsigned pkd = (unsigned)f2bf(v) | ((unsigned)f2bf(vo) << 16);
                    int col = col_base + nt * 16 + c;  // even
                    g1[(size_t)(col >> 5) * (N_NODES * 16) + (size_t)row * 16 + ((col & 31) >> 1)] = pkd;
                }
            }
        }
    }
}

// ---------------------------------------------------------------------------
// Aggregation 1 + bias + ReLU + per-slice GEMM2 partial. Feature-sliced,
// XCD-pinned (blockIdx&7 -> slice plane, 3.2MB, L2-resident per XCD).
// v5 = R2's proven depth-2 ping-pong (VGPR <= 64, 8 waves/SIMD cap) with
// the shfl index distribution replaced by direct aligned uint2 index loads
// (peel rs&3 edges). Index load for the NEXT batch is hoisted before the
// current batch's consume so its latency hides under the ~128cy ACC phase;
// gathers then issue with indices already in-register (no ds_bpermute on
// the dependent chain).
// ---------------------------------------------------------------------------
__global__ __launch_bounds__(256) void agg1_sliced(const uint4* __restrict__ g1,
                                                   const int* __restrict__ rs,
                                                   const int* __restrict__ re,
                                                   const unsigned short* __restrict__ csr_src,
                                                   const float* __restrict__ dis,
                                                   const float* __restrict__ b1,
                                                   const float* __restrict__ W2,
                                                   float* __restrict__ g2p) {
    __shared__ float w2s[32 * 16];      // this slice's W2 rows (2 KB)
    __shared__ float rbuf[4][16][36];   // per wave/group r vector (32 feats + pad)
    int tid = threadIdx.x;
    int bi = blockIdx.x;
    int bucket = bi >> 4;               // 196
    int xcd = bi & 7;
    int slice = xcd >> 1;               // XCD pair {2s,2s+1} -> slice s
    int quarter = ((bi >> 3) & 1) * 2 + (xcd & 1);

    for (int i = tid; i < 512; i += 256) w2s[i] = W2[slice * 512 + i];
    __syncthreads();

    int wave = tid >> 6, lane = tid & 63;
    int g = lane >> 2, m4 = lane & 3;   // group g owns a node; lane m4 covers feats 8*m4..8*m4+7
    const uint4* plane = g1 + (size_t)slice * (N_NODES * 4);
    float* gp = g2p + (size_t)slice * ((size_t)N_NODES * 16);
    int node = bucket * 256 + quarter * 64 + wave * 16 + g;
    bool alive = (node < N_NODES);

#define ACC8(u) do { a0 += bflo((u).x); a1 += bfhi((u).x); a2 += bflo((u).y); a3 += bfhi((u).y); \
                     a4 += bflo((u).z); a5 += bfhi((u).z); a6 += bflo((u).w); a7 += bfhi((u).w); } while (0)
#define GATH(IV, U0, U1, U2, U3) do {                       \
        int j0_ = (int)((IV).x & 0xffffu);                  \
        int j1_ = (int)((IV).x >> 16);                      \
        int j2_ = (int)((IV).y & 0xffffu);                  \
        int j3_ = (int)((IV).y >> 16);                      \
        U0 = plane[(size_t)j0_ * 4 + m4];                   \
        U1 = plane[(size_t)j1_ * 4 + m4];                   \
        U2 = plane[(size_t)j2_ * 4 + m4];                   \
        U3 = plane[(size_t)j3_ * 4 + m4];                   \
    } while (0)

    if (alive) {
        uint4 su = plane[(size_t)node * 4 + m4];   // self loop (g1 carries dis[src])
        float a0 = bflo(su.x), a1 = bfhi(su.x), a2 = bflo(su.y), a3 = bfhi(su.y);
        float a4 = bflo(su.z), a5 = bfhi(su.z), a6 = bflo(su.w), a7 = bfhi(su.w);
        int e = rs[node], e1v = re[node];
        // peel to 4-edge alignment so uint2 index loads are 8B-aligned
        while ((e & 3) && e < e1v) {
            int j = csr_src[e];
            uint4 u = plane[(size_t)j * 4 + m4];
            ACC8(u);
            ++e;
        }
        int nb = (e1v - e) >> 2;   // full batches of 4
        if (nb >= 2) {
            uint2 Ia = *(const uint2*)&csr_src[e];
            uint2 Ib = *(const uint2*)&csr_src[e + 4];
            uint4 A0, A1, A2, A3, B0, B1, B2, B3;
            GATH(Ia, A0, A1, A2, A3);
            GATH(Ib, B0, B1, B2, B3);
            __builtin_amdgcn_sched_barrier(0);
            int b = 2;
            while (b + 2 <= nb) {
                Ia = *(const uint2*)&csr_src[e + 4 * b];      // idx for next A, early
                ACC8(A0); ACC8(A1); ACC8(A2); ACC8(A3);       // consume A (hides Ia)
                GATH(Ia, A0, A1, A2, A3);                     // reissue A
                __builtin_amdgcn_sched_barrier(0);
                Ib = *(const uint2*)&csr_src[e + 4 * b + 4];  // idx for next B, early
                ACC8(B0); ACC8(B1); ACC8(B2); ACC8(B3);       // consume B (hides Ib)
                GATH(Ib, B0, B1, B2, B3);                     // reissue B
                __builtin_amdgcn_sched_barrier(0);
                b += 2;
            }
            int rem = nb - b;   // 0 or 1
            ACC8(A0); ACC8(A1); ACC8(A2); ACC8(A3);
            if (rem) {
                Ia = *(const uint2*)&csr_src[e + 4 * b];
                GATH(Ia, A0, A1, A2, A3);
            }
            ACC8(B0); ACC8(B1); ACC8(B2); ACC8(B3);
            if (rem) { ACC8(A0); ACC8(A1); ACC8(A2); ACC8(A3); }
            e += 4 * nb;
        } else if (nb >= 1) {
            uint2 Iv = *(const uint2*)&csr_src[e];
            uint4 U0, U1, U2, U3;
            GATH(Iv, U0, U1, U2, U3);
            ACC8(U0); ACC8(U1); ACC8(U2); ACC8(U3);
            e += 4;
        }
        while (e < e1v) {   // tail 0..3 edges
            int j = csr_src[e];
            uint4 u = plane[(size_t)j * 4 + m4];
            ACC8(u);
            ++e;
        }

        // bias + ReLU, publish r (lane owns feats 8*m4..8*m4+7)
        float dv = dis[node];
        float4 bb0 = *(const float4*)&b1[slice * 32 + 8 * m4];
        float4 bb1 = *(const float4*)&b1[slice * 32 + 8 * m4 + 4];
        float4 r0, r1;
        r0.x = fmaxf(fmaf(dv, a0, bb0.x), 0.f);
        r0.y = fmaxf(fmaf(dv, a1, bb0.y), 0.f);
        r0.z = fmaxf(fmaf(dv, a2, bb0.z), 0.f);
        r0.w = fmaxf(fmaf(dv, a3, bb0.w), 0.f);
        r1.x = fmaxf(fmaf(dv, a4, bb1.x), 0.f);
        r1.y = fmaxf(fmaf(dv, a5, bb1.y), 0.f);
        r1.z = fmaxf(fmaf(dv, a6, bb1.z), 0.f);
        r1.w = fmaxf(fmaf(dv, a7, bb1.w), 0.f);
        *(float4*)&rbuf[wave][g][8 * m4] = r0;
        *(float4*)&rbuf[wave][g][8 * m4 + 4] = r1;
    }
    __builtin_amdgcn_sched_barrier(0);   // wave-synchronous LDS: keep reads after writes
    if (alive) {
        // GEMM2 partial: lane m4 computes classes 4*m4..4*m4+3 over all 32 feats
        float p0 = 0.f, p1 = 0.f, p2 = 0.f, p3 = 0.f;
#pragma unroll
        for (int fb = 0; fb < 8; ++fb) {
            float4 rv = *(const float4*)&rbuf[wave][g][fb * 4];
            float4 w0 = *(const float4*)&w2s[(fb * 4 + 0) * 16 + 4 * m4];
            float4 w1 = *(const float4*)&w2s[(fb * 4 + 1) * 16 + 4 * m4];
            float4 w2 = *(const float4*)&w2s[(fb * 4 + 2) * 16 + 4 * m4];
            float4 w3 = *(const float4*)&w2s[(fb * 4 + 3) * 16 + 4 * m4];
            p0 = fmaf(rv.x, w0.x, p0); p1 = fmaf(rv.x, w0.y, p1);
            p2 = fmaf(rv.x, w0.z, p2); p3 = fmaf(rv.x, w0.w, p3);
            p0 = fmaf(rv.y, w1.x, p0); p1 = fmaf(rv.y, w1.y, p1);
            p2 = fmaf(rv.y, w1.z, p2); p3 = fmaf(rv.y, w1.w, p3);
            p0 = fmaf(rv.z, w2.x, p0); p1 = fmaf(rv.z, w2.y, p1);
            p2 = fmaf(rv.z, w2.z, p2); p3 = fmaf(rv.z, w2.w, p3);
            p0 = fmaf(rv.w, w3.x, p0); p1 = fmaf(rv.w, w3.y, p1);
            p2 = fmaf(rv.w, w3.z, p2); p3 = fmaf(rv.w, w3.w, p3);
        }
        float4 pv; pv.x = p0; pv.y = p1; pv.z = p2; pv.w = p3;
        *(float4*)&gp[(size_t)node * 16 + 4 * m4] = pv;
    }
#undef GATH
#undef ACC8
}

// ---------------------------------------------------------------------------
// Combine the 4 per-slice GEMM2 partials + dis scale, in place into plane 0.
// ---------------------------------------------------------------------------
__global__ __launch_bounds__(256) void g2_reduce(float* __restrict__ g2p,
                                                 const float* __restrict__ dis) {
    int i = blockIdx.x * 256 + threadIdx.x;   // one float4 (4 classes)
    if (i >= N_NODES * 4) return;
    const size_t PS = (size_t)N_NODES * 16 / 4;  // plane stride in float4
    const float4* p = (const float4*)g2p;
    float4 a = p[i];
    float4 b = p[i + PS];
    float4 c = p[i + 2 * PS];
    float4 d = p[i + 3 * PS];
    float dv = dis[i >> 2];
    float4 r;
    r.x = dv * ((a.x + b.x) + (c.x + d.x));
    r.y = dv * ((a.y + b.y) + (c.y + d.y));
    r.z = dv * ((a.z + b.z) + (c.z + d.z));
    r.w = dv * ((a.w + b.w) + (c.w + d.w));
    ((float4*)g2p)[i] = r;
}

// ---------------------------------------------------------------------------
// Aggregation 2 + bias + logits + softmax. v5: depth-2 ping-pong with
// direct uint2 index loads (no shfl), index hoisted before consume.
// g2 (3.2 MB) is L2-resident per XCD by size.
// ---------------------------------------------------------------------------
__global__ __launch_bounds__(256) void agg2_softmax(const float4* __restrict__ g2,
                                                    const int* __restrict__ rs,
                                                    const int* __restrict__ re,
                                                    const unsigned short* __restrict__ csr_src,
                                                    const float* __restrict__ dis,
                                                    const float* __restrict__ b2,
                                                    float* __restrict__ out) {
    int tid = threadIdx.x;
    int wave = tid >> 6, lane = tid & 63;
    int g = lane >> 2, m4 = lane & 3;   // group owns a node; lane m4 covers classes 4*m4..4*m4+3
    int node = blockIdx.x * 64 + wave * 16 + g;
    if (node >= N_NODES) return;

    float4 acc = g2[(size_t)node * 4 + m4];   // self loop

#define ACC4(u) do { acc.x += (u).x; acc.y += (u).y; acc.z += (u).z; acc.w += (u).w; } while (0)
#define GATH4(IV, U0, U1, U2, U3) do {                      \
        int j0_ = (int)((IV).x & 0xffffu);                  \
        int j1_ = (int)((IV).x >> 16);                      \
        int j2_ = (int)((IV).y & 0xffffu);                  \
        int j3_ = (int)((IV).y >> 16);                      \
        U0 = g2[(size_t)j0_ * 4 + m4];                      \
        U1 = g2[(size_t)j1_ * 4 + m4];                      \
        U2 = g2[(size_t)j2_ * 4 + m4];                      \
        U3 = g2[(size_t)j3_ * 4 + m4];                      \
    } while (0)

    int e = rs[node], e1v = re[node];
    while ((e & 3) && e < e1v) {
        int j = csr_src[e];
        float4 u = g2[(size_t)j * 4 + m4];
        ACC4(u);
        ++e;
    }
    int nb = (e1v - e) >> 2;
    if (nb >= 2) {
        uint2 Ia = *(const uint2*)&csr_src[e];
        uint2 Ib = *(const uint2*)&csr_src[e + 4];
        float4 A0, A1, A2, A3, B0, B1, B2, B3;
        GATH4(Ia, A0, A1, A2, A3);
        GATH4(Ib, B0, B1, B2, B3);
        __builtin_amdgcn_sched_barrier(0);
        int b = 2;
        while (b + 2 <= nb) {
            Ia = *(const uint2*)&csr_src[e + 4 * b];
            ACC4(A0); ACC4(A1); ACC4(A2); ACC4(A3);
            GATH4(Ia, A0, A1, A2, A3);
            __builtin_amdgcn_sched_barrier(0);
            Ib = *(const uint2*)&csr_src[e + 4 * b + 4];
            ACC4(B0); ACC4(B1); ACC4(B2); ACC4(B3);
            GATH4(Ib, B0, B1, B2, B3);
            __builtin_amdgcn_sched_barrier(0);
            b += 2;
        }
        int rem = nb - b;
        ACC4(A0); ACC4(A1); ACC4(A2); ACC4(A3);
        if (rem) {
            Ia = *(const uint2*)&csr_src[e + 4 * b];
            GATH4(Ia, A0, A1, A2, A3);
        }
        ACC4(B0); ACC4(B1); ACC4(B2); ACC4(B3);
        if (rem) { ACC4(A0); ACC4(A1); ACC4(A2); ACC4(A3); }
        e += 4 * nb;
    } else if (nb >= 1) {
        uint2 Iv = *(const uint2*)&csr_src[e];
        float4 U0, U1, U2, U3;
        GATH4(Iv, U0, U1, U2, U3);
        ACC4(U0); ACC4(U1); ACC4(U2); ACC4(U3);
        e += 4;
    }
    while (e < e1v) {
        int j = csr_src[e];
        float4 u = g2[(size_t)j * 4 + m4];
        ACC4(u);
        ++e;
    }
#undef GATH4
#undef ACC4

    float dv = dis[node];
    float4 bb = *(const float4*)&b2[4 * m4];
    float4 lg;
    lg.x = fmaf(dv, acc.x, bb.x);
    lg.y = fmaf(dv, acc.y, bb.y);
    lg.z = fmaf(dv, acc.z, bb.z);
    lg.w = fmaf(dv, acc.w, bb.w);
    ((float4*)out)[(size_t)node * 4 + m4] = lg;

    // softmax over 16 classes = 4 lanes x 4
    float m = fmaxf(fmaxf(lg.x, lg.y), fmaxf(lg.z, lg.w));
    m = fmaxf(m, __shfl_xor(m, 1));
    m = fmaxf(m, __shfl_xor(m, 2));
    float4 ex;
    ex.x = expf(lg.x - m); ex.y = expf(lg.y - m);
    ex.z = expf(lg.z - m); ex.w = expf(lg.w - m);
    float s = (ex.x + ex.y) + (ex.z + ex.w);
    s += __shfl_xor(s, 1);
    s += __shfl_xor(s, 2);
    float inv = 1.0f / s;
    ex.x *= inv; ex.y *= inv; ex.z *= inv; ex.w *= inv;
    ((float4*)out)[(size_t)N_NODES * 4 + (size_t)node * 4 + m4] = ex;
}

// ---------------------------------------------------------------------------

extern "C" void kernel_launch(void* const* d_in, const int* in_sizes, int n_in,
                              void* d_out, int out_size, void* d_ws, size_t ws_size,
                              hipStream_t stream) {
    const float* x  = (const float*)d_in[0];
    const int*   ei = (const int*)d_in[1];
    const float* W1 = (const float*)d_in[2];
    const float* b1 = (const float*)d_in[3];
    const float* W2 = (const float*)d_in[4];
    const float* b2 = (const float*)d_in[5];
    float* out = (float*)d_out;

    char* ws = (char*)d_ws;
    size_t off = 0;
    auto alloc = [&](size_t bytes) -> char* {
        char* p = ws + off;
        off = (off + bytes + 511) & ~(size_t)511;
        return p;
    };
    int*   cursor   = (int*)alloc(256 * 4);
    float* dis      = (float*)alloc(N_NODES * 4);
    int*   rs       = (int*)alloc(N_NODES * 4);
    int*   re       = (int*)alloc(N_NODES * 4);
    unsigned short* w1t = (unsigned short*)alloc((size_t)HIDDEN * IN_FEAT * 2);
    unsigned short* csr_src = (unsigned short*)alloc((size_t)NBKT * BCAP * 2);  // holey
    unsigned int* g1 = (unsigned int*)alloc((size_t)N_NODES * 64 * 4);          // slice-major: 4 x [N][16dw]
    float* g2p      = (float*)alloc(4 * (size_t)N_NODES * N_CLASSES * 4);       // per-slice GEMM2 partials
    // sorted edges (196*10240*4 = 8.0MB) alias g1's slab (12.8MB): dead before gemm1.
    unsigned int* sorted = (unsigned int*)g1;
    (void)ws_size; (void)in_sizes; (void)n_in; (void)out_size;

    const int* src = ei;
    const int* dst = ei + N_EDGES;

    hipMemsetAsync(cursor, 0, 256 * 4, stream);
    scatter_edges2<<<NCHK, 256, 0, stream>>>(src, dst, cursor, sorted, W1, w1t);
    build_csr2<<<NBKT, 256, 0, stream>>>(sorted, cursor, rs, re, dis, csr_src);

    gemm1_mfma<<<(N_NODES + 63) / 64, 256, 0, stream>>>(x, w1t, dis, g1);
    agg1_sliced<<<NBKT * 16, 256, 0, stream>>>((const uint4*)g1, rs, re, csr_src, dis, b1, W2, g2p);
    g2_reduce<<<(N_NODES * 4 + 255) / 256, 256, 0, stream>>>(g2p, dis);
    agg2_softmax<<<N_NODES / 64 + 1, 256, 0, stream>>>((const float4*)g2p, rs, re, csr_src, dis, b2, out);
}

// Round 6
// 224.267 us; speedup vs baseline: 4.2440x; 1.0169x over previous
//
#include <hip/hip_runtime.h>
#include <hip/hip_bf16.h>
#include <math.h>

#define N_NODES 50000
#define N_EDGES 1600000
#define IN_FEAT 256
#define HIDDEN 128
#define N_CLASSES 16

#define ECHUNK 2048
#define NCHK 782    // ceil(1600000/2048)
#define NBKT 196    // ceil(50000/256) buckets of 256 nodes
#define BCAP 10240  // per-bucket capacity: mean 8192, std ~90 -> +23 sigma
#define CSTR 16     // cursor stride (ints): 1 counter per 64B line

typedef __attribute__((ext_vector_type(8))) short short8;   // 8 bf16 (A/B frag)
typedef __attribute__((ext_vector_type(4))) float floatx4;  // C/D frag

// bf16 round-to-nearest-even (scalar integer path)
__device__ __forceinline__ unsigned short f2bf(float f) {
    unsigned u = __float_as_uint(f);
    return (unsigned short)((u + 0x7fffu + ((u >> 16) & 1u)) >> 16);
}

// HW packed fp32->bf16x2
__device__ __forceinline__ unsigned pk2bf(float a, float b) {
    __hip_bfloat162 h = __float22bfloat162_rn(make_float2(a, b));
    union { __hip_bfloat162 h; unsigned u; } cv;
    cv.h = h;
    return cv.u;
}

__device__ __forceinline__ float bflo(unsigned u) { return __uint_as_float(u << 16); }
__device__ __forceinline__ float bfhi(unsigned u) { return __uint_as_float(u & 0xffff0000u); }

// ---------------------------------------------------------------------------
// Prep: fixed-capacity buckets. v6: 782 blocks (2048 edges each) for >1
// block/CU; cursor counters padded to 1/line to keep reservation atomics
// parallel across L2 slices. Blocks 0..127 also transpose W1 -> w1t.
// ---------------------------------------------------------------------------
__global__ __launch_bounds__(256) void scatter_edges2(const int* __restrict__ src,
                                                      const int* __restrict__ dst,
                                                      int* __restrict__ cursor,   // [256*CSTR], zeroed
                                                      unsigned int* __restrict__ sorted,
                                                      const float* __restrict__ W1,
                                                      unsigned short* __restrict__ w1t) {
    __shared__ int hloc[256];
    int t = threadIdx.x;
    hloc[t] = 0;
    if (blockIdx.x < HIDDEN)
        w1t[blockIdx.x * IN_FEAT + t] = f2bf(W1[t * HIDDEN + blockIdx.x]);
    __syncthreads();
    int base = blockIdx.x * ECHUNK;
    int end = min(base + ECHUNK, N_EDGES);
    for (int i = base + t; i < end; i += 256)
        atomicAdd(&hloc[dst[i] >> 8], 1);
    __syncthreads();
    int cnt = hloc[t];
    int lbase = 0;
    if (cnt > 0) lbase = t * BCAP + atomicAdd(&cursor[t * CSTR], cnt);  // block's base in bucket t
    __syncthreads();
    hloc[t] = lbase;  // reuse as local cursor
    __syncthreads();
    for (int i = base + t; i < end; i += 256) {
        int d = dst[i];
        int s = src[i];
        int pos = atomicAdd(&hloc[d >> 8], 1);
        sorted[pos] = ((unsigned)d << 16) | (unsigned)s;
    }
}

// v6: 512 threads/block -> halves each serial pass (16 edges/thread).
__global__ __launch_bounds__(512) void build_csr2(const unsigned int* __restrict__ sorted,
                                                  const int* __restrict__ cursor,
                                                  int* __restrict__ rs,
                                                  int* __restrict__ re,
                                                  float* __restrict__ dis,
                                                  unsigned short* __restrict__ csr_src) {
    __shared__ int cnt[256];
    __shared__ int roff[256];
    int t = threadIdx.x;      // 0..511
    int bkt = blockIdx.x;
    int ebase = bkt * BCAP;
    int eend = ebase + cursor[bkt * CSTR];
    if (t < 256) cnt[t] = 0;
    __syncthreads();
    for (int i = ebase + t; i < eend; i += 512)
        atomicAdd(&cnt[(sorted[i] >> 16) & 255], 1);
    __syncthreads();
    int v = 0;
    if (t < 256) { v = cnt[t]; roff[t] = v; }
    __syncthreads();
    for (int off = 1; off < 256; off <<= 1) {
        int x = (t < 256 && t >= off) ? roff[t - off] : 0;
        __syncthreads();
        if (t < 256) roff[t] += x;
        __syncthreads();
    }
    if (t < 256) {
        int excl = roff[t] - v;
        int node = bkt * 256 + t;
        if (node < N_NODES) {
            rs[node] = ebase + excl;
            re[node] = ebase + excl + v;
            dis[node] = 1.0f / sqrtf((float)(v + 1));  // +1 self loop
        }
        cnt[t] = ebase + excl;  // reuse as cursor
    }
    __syncthreads();
    for (int i = ebase + t; i < eend; i += 512) {
        unsigned e = sorted[i];
        int pos = atomicAdd(&cnt[(e >> 16) & 255], 1);
        csr_src[pos] = (unsigned short)(e & 0xffffu);
    }
}

// ---------------------------------------------------------------------------
// GEMM1 via MFMA with LDS-staged A (global_load_lds, width 16).
// Output layout SLICE-MAJOR: g1[slice][node][16 dwords]; each 32-feature
// slice is a contiguous 3.2 MB plane (fits one XCD's 4 MB L2).
// ---------------------------------------------------------------------------
#define XCH 260   // dwords per 8-row chunk: 8*32 + 4 pad

__global__ __launch_bounds__(256) void gemm1_mfma(const float* __restrict__ x,
                                                  const unsigned short* __restrict__ w1t,
                                                  const float* __restrict__ dis,
                                                  unsigned int* __restrict__ g1) {
    __shared__ float xs[2][8 * XCH];   // 2 x 8320 B
    int tid = threadIdx.x;
    int w = tid >> 6;
    int lane = tid & 63;
    int quad = lane >> 4;
    int c = lane & 15;
    int row_base = blockIdx.x * 64;
    int wrow = (w >> 1) * 32;        // wave's row offset in tile
    int col_base = (w & 1) * 64;

    int st_row = min(row_base + 16 * w + (lane >> 3), N_NODES - 1);       // chunk 2w
    int st_row2 = min(row_base + 16 * w + 8 + (lane >> 3), N_NODES - 1);  // chunk 2w+1
    const float* gp1 = x + (size_t)st_row * IN_FEAT + (lane & 7) * 4;
    const float* gp2 = x + (size_t)st_row2 * IN_FEAT + (lane & 7) * 4;

    floatx4 acc[2][4] = {};
    const unsigned short* bp[4];
#pragma unroll
    for (int nt = 0; nt < 4; ++nt)
        bp[nt] = w1t + (size_t)(col_base + nt * 16 + c) * IN_FEAT + quad * 8;

    int dwoff[2];
#pragma unroll
    for (int rt = 0; rt < 2; ++rt) {
        int rit = wrow + rt * 16 + c;
        dwoff[rt] = (rit >> 3) * XCH + (rit & 7) * 32 + quad * 8;
    }

#define STAGE(buf, k0)                                                                  \
    do {                                                                                \
        __builtin_amdgcn_global_load_lds(                                               \
            (const __attribute__((address_space(1))) void*)(gp1 + (k0)),                \
            (__attribute__((address_space(3))) void*)&xs[buf][(2 * w) * XCH], 16, 0, 0);\
        __builtin_amdgcn_global_load_lds(                                               \
            (const __attribute__((address_space(1))) void*)(gp2 + (k0)),                \
            (__attribute__((address_space(3))) void*)&xs[buf][(2 * w + 1) * XCH], 16, 0, 0);\
    } while (0)

    STAGE(0, 0);
    __syncthreads();

    int buf = 0;
#pragma unroll
    for (int kk = 0; kk < 8; ++kk) {
        if (kk < 7) STAGE(buf ^ 1, (kk + 1) * 32);
        short8 b[4];
#pragma unroll
        for (int nt = 0; nt < 4; ++nt)
            b[nt] = *(const short8*)(bp[nt] + kk * 32);
        short8 a[2];
#pragma unroll
        for (int rt = 0; rt < 2; ++rt) {
            float4 f0 = *(const float4*)&xs[buf][dwoff[rt]];
            float4 f1 = *(const float4*)&xs[buf][dwoff[rt] + 4];
            union { short8 s; unsigned u[4]; } au;
            au.u[0] = pk2bf(f0.x, f0.y);
            au.u[1] = pk2bf(f0.z, f0.w);
            au.u[2] = pk2bf(f1.x, f1.y);
            au.u[3] = pk2bf(f1.z, f1.w);
            a[rt] = au.s;
        }
#pragma unroll
        for (int rt = 0; rt < 2; ++rt)
#pragma unroll
            for (int nt = 0; nt < 4; ++nt)
                acc[rt][nt] = __builtin_amdgcn_mfma_f32_16x16x32_bf16(a[rt], b[nt], acc[rt][nt], 0, 0, 0);
        __syncthreads();   // drains stage vmcnt + protects buf reuse
        buf ^= 1;
    }
#undef STAGE

    // Epilogue: dis scale, pair adjacent cols via shfl, pack bf16x2, store
    // slice-major. C/D layout: col = lane&15, row = quad*4 + reg.
    bool evenlane = (lane & 1) == 0;
#pragma unroll
    for (int rt = 0; rt < 2; ++rt) {
#pragma unroll
        for (int reg = 0; reg < 4; ++reg) {
            int row = row_base + wrow + rt * 16 + quad * 4 + reg;
            float dv = dis[min(row, N_NODES - 1)];
#pragma unroll
            for (int nt = 0; nt < 4; ++nt) {
                float v = acc[rt][nt][reg] * dv;
                float vo = __shfl_xor(v, 1);
                if (evenlane && row < N_NODES) {
                    unsigned pkd = (unsigned)f2bf(v) | ((unsigned)f2bf(vo) << 16);
                    int col = col_base + nt * 16 + c;  // even
                    g1[(size_t)(col >> 5) * (N_NODES * 16) + (size_t)row * 16 + ((col & 31) >> 1)] = pkd;
                }
            }
        }
    }
}

// ---------------------------------------------------------------------------
// Aggregation 1 + bias + ReLU + per-slice GEMM2 partial. Feature-sliced,
// XCD-pinned (blockIdx&7 -> slice plane, 3.2MB, L2-resident per XCD).
// FROZEN at the measured random-gather wall (~8 TB/s of 64B line visits):
// depth-2 ping-pong, direct aligned uint2 index loads, VGPR 52 (<64 cliff).
// ---------------------------------------------------------------------------
__global__ __launch_bounds__(256) void agg1_sliced(const uint4* __restrict__ g1,
                                                   const int* __restrict__ rs,
                                                   const int* __restrict__ re,
                                                   const unsigned short* __restrict__ csr_src,
                                                   const float* __restrict__ dis,
                                                   const float* __restrict__ b1,
                                                   const float* __restrict__ W2,
                                                   float* __restrict__ g2p) {
    __shared__ float w2s[32 * 16];      // this slice's W2 rows (2 KB)
    __shared__ float rbuf[4][16][36];   // per wave/group r vector (32 feats + pad)
    int tid = threadIdx.x;
    int bi = blockIdx.x;
    int bucket = bi >> 4;               // 196
    int xcd = bi & 7;
    int slice = xcd >> 1;               // XCD pair {2s,2s+1} -> slice s
    int quarter = ((bi >> 3) & 1) * 2 + (xcd & 1);

    for (int i = tid; i < 512; i += 256) w2s[i] = W2[slice * 512 + i];
    __syncthreads();

    int wave = tid >> 6, lane = tid & 63;
    int g = lane >> 2, m4 = lane & 3;   // group g owns a node; lane m4 covers feats 8*m4..8*m4+7
    const uint4* plane = g1 + (size_t)slice * (N_NODES * 4);
    float* gp = g2p + (size_t)slice * ((size_t)N_NODES * 16);
    int node = bucket * 256 + quarter * 64 + wave * 16 + g;
    bool alive = (node < N_NODES);

#define ACC8(u) do { a0 += bflo((u).x); a1 += bfhi((u).x); a2 += bflo((u).y); a3 += bfhi((u).y); \
                     a4 += bflo((u).z); a5 += bfhi((u).z); a6 += bflo((u).w); a7 += bfhi((u).w); } while (0)
#define GATH(IV, U0, U1, U2, U3) do {                       \
        int j0_ = (int)((IV).x & 0xffffu);                  \
        int j1_ = (int)((IV).x >> 16);                      \
        int j2_ = (int)((IV).y & 0xffffu);                  \
        int j3_ = (int)((IV).y >> 16);                      \
        U0 = plane[(size_t)j0_ * 4 + m4];                   \
        U1 = plane[(size_t)j1_ * 4 + m4];                   \
        U2 = plane[(size_t)j2_ * 4 + m4];                   \
        U3 = plane[(size_t)j3_ * 4 + m4];                   \
    } while (0)

    if (alive) {
        uint4 su = plane[(size_t)node * 4 + m4];   // self loop (g1 carries dis[src])
        float a0 = bflo(su.x), a1 = bfhi(su.x), a2 = bflo(su.y), a3 = bfhi(su.y);
        float a4 = bflo(su.z), a5 = bfhi(su.z), a6 = bflo(su.w), a7 = bfhi(su.w);
        int e = rs[node], e1v = re[node];
        // peel to 4-edge alignment so uint2 index loads are 8B-aligned
        while ((e & 3) && e < e1v) {
            int j = csr_src[e];
            uint4 u = plane[(size_t)j * 4 + m4];
            ACC8(u);
            ++e;
        }
        int nb = (e1v - e) >> 2;   // full batches of 4
        if (nb >= 2) {
            uint2 Ia = *(const uint2*)&csr_src[e];
            uint2 Ib = *(const uint2*)&csr_src[e + 4];
            uint4 A0, A1, A2, A3, B0, B1, B2, B3;
            GATH(Ia, A0, A1, A2, A3);
            GATH(Ib, B0, B1, B2, B3);
            __builtin_amdgcn_sched_barrier(0);
            int b = 2;
            while (b + 2 <= nb) {
                Ia = *(const uint2*)&csr_src[e + 4 * b];      // idx for next A, early
                ACC8(A0); ACC8(A1); ACC8(A2); ACC8(A3);       // consume A (hides Ia)
                GATH(Ia, A0, A1, A2, A3);                     // reissue A
                __builtin_amdgcn_sched_barrier(0);
                Ib = *(const uint2*)&csr_src[e + 4 * b + 4];  // idx for next B, early
                ACC8(B0); ACC8(B1); ACC8(B2); ACC8(B3);       // consume B (hides Ib)
                GATH(Ib, B0, B1, B2, B3);                     // reissue B
                __builtin_amdgcn_sched_barrier(0);
                b += 2;
            }
            int rem = nb - b;   // 0 or 1
            ACC8(A0); ACC8(A1); ACC8(A2); ACC8(A3);
            if (rem) {
                Ia = *(const uint2*)&csr_src[e + 4 * b];
                GATH(Ia, A0, A1, A2, A3);
            }
            ACC8(B0); ACC8(B1); ACC8(B2); ACC8(B3);
            if (rem) { ACC8(A0); ACC8(A1); ACC8(A2); ACC8(A3); }
            e += 4 * nb;
        } else if (nb >= 1) {
            uint2 Iv = *(const uint2*)&csr_src[e];
            uint4 U0, U1, U2, U3;
            GATH(Iv, U0, U1, U2, U3);
            ACC8(U0); ACC8(U1); ACC8(U2); ACC8(U3);
            e += 4;
        }
        while (e < e1v) {   // tail 0..3 edges
            int j = csr_src[e];
            uint4 u = plane[(size_t)j * 4 + m4];
            ACC8(u);
            ++e;
        }

        // bias + ReLU, publish r (lane owns feats 8*m4..8*m4+7)
        float dv = dis[node];
        float4 bb0 = *(const float4*)&b1[slice * 32 + 8 * m4];
        float4 bb1 = *(const float4*)&b1[slice * 32 + 8 * m4 + 4];
        float4 r0, r1;
        r0.x = fmaxf(fmaf(dv, a0, bb0.x), 0.f);
        r0.y = fmaxf(fmaf(dv, a1, bb0.y), 0.f);
        r0.z = fmaxf(fmaf(dv, a2, bb0.z), 0.f);
        r0.w = fmaxf(fmaf(dv, a3, bb0.w), 0.f);
        r1.x = fmaxf(fmaf(dv, a4, bb1.x), 0.f);
        r1.y = fmaxf(fmaf(dv, a5, bb1.y), 0.f);
        r1.z = fmaxf(fmaf(dv, a6, bb1.z), 0.f);
        r1.w = fmaxf(fmaf(dv, a7, bb1.w), 0.f);
        *(float4*)&rbuf[wave][g][8 * m4] = r0;
        *(float4*)&rbuf[wave][g][8 * m4 + 4] = r1;
    }
    __builtin_amdgcn_sched_barrier(0);   // wave-synchronous LDS: keep reads after writes
    if (alive) {
        // GEMM2 partial: lane m4 computes classes 4*m4..4*m4+3 over all 32 feats
        float p0 = 0.f, p1 = 0.f, p2 = 0.f, p3 = 0.f;
#pragma unroll
        for (int fb = 0; fb < 8; ++fb) {
            float4 rv = *(const float4*)&rbuf[wave][g][fb * 4];
            float4 w0 = *(const float4*)&w2s[(fb * 4 + 0) * 16 + 4 * m4];
            float4 w1 = *(const float4*)&w2s[(fb * 4 + 1) * 16 + 4 * m4];
            float4 w2 = *(const float4*)&w2s[(fb * 4 + 2) * 16 + 4 * m4];
            float4 w3 = *(const float4*)&w2s[(fb * 4 + 3) * 16 + 4 * m4];
            p0 = fmaf(rv.x, w0.x, p0); p1 = fmaf(rv.x, w0.y, p1);
            p2 = fmaf(rv.x, w0.z, p2); p3 = fmaf(rv.x, w0.w, p3);
            p0 = fmaf(rv.y, w1.x, p0); p1 = fmaf(rv.y, w1.y, p1);
            p2 = fmaf(rv.y, w1.z, p2); p3 = fmaf(rv.y, w1.w, p3);
            p0 = fmaf(rv.z, w2.x, p0); p1 = fmaf(rv.z, w2.y, p1);
            p2 = fmaf(rv.z, w2.z, p2); p3 = fmaf(rv.z, w2.w, p3);
            p0 = fmaf(rv.w, w3.x, p0); p1 = fmaf(rv.w, w3.y, p1);
            p2 = fmaf(rv.w, w3.z, p2); p3 = fmaf(rv.w, w3.w, p3);
        }
        float4 pv; pv.x = p0; pv.y = p1; pv.z = p2; pv.w = p3;
        *(float4*)&gp[(size_t)node * 16 + 4 * m4] = pv;
    }
#undef GATH
#undef ACC8
}

// ---------------------------------------------------------------------------
// Combine the 4 per-slice GEMM2 partials + dis scale, in place into plane 0.
// ---------------------------------------------------------------------------
__global__ __launch_bounds__(256) void g2_reduce(float* __restrict__ g2p,
                                                 const float* __restrict__ dis) {
    int i = blockIdx.x * 256 + threadIdx.x;   // one float4 (4 classes)
    if (i >= N_NODES * 4) return;
    const size_t PS = (size_t)N_NODES * 16 / 4;  // plane stride in float4
    const float4* p = (const float4*)g2p;
    float4 a = p[i];
    float4 b = p[i + PS];
    float4 c = p[i + 2 * PS];
    float4 d = p[i + 3 * PS];
    float dv = dis[i >> 2];
    float4 r;
    r.x = dv * ((a.x + b.x) + (c.x + d.x));
    r.y = dv * ((a.y + b.y) + (c.y + d.y));
    r.z = dv * ((a.z + b.z) + (c.z + d.z));
    r.w = dv * ((a.w + b.w) + (c.w + d.w));
    ((float4*)g2p)[i] = r;
}

// ---------------------------------------------------------------------------
// Aggregation 2 + bias + logits + softmax. Depth-2 ping-pong with direct
// uint2 index loads. g2 (3.2 MB) is L2-resident per XCD by size.
// ---------------------------------------------------------------------------
__global__ __launch_bounds__(256) void agg2_softmax(const float4* __restrict__ g2,
                                                    const int* __restrict__ rs,
                                                    const int* __restrict__ re,
                                                    const unsigned short* __restrict__ csr_src,
                                                    const float* __restrict__ dis,
                                                    const float* __restrict__ b2,
                                                    float* __restrict__ out) {
    int tid = threadIdx.x;
    int wave = tid >> 6, lane = tid & 63;
    int g = lane >> 2, m4 = lane & 3;   // group owns a node; lane m4 covers classes 4*m4..4*m4+3
    int node = blockIdx.x * 64 + wave * 16 + g;
    if (node >= N_NODES) return;

    float4 acc = g2[(size_t)node * 4 + m4];   // self loop

#define ACC4(u) do { acc.x += (u).x; acc.y += (u).y; acc.z += (u).z; acc.w += (u).w; } while (0)
#define GATH4(IV, U0, U1, U2, U3) do {                      \
        int j0_ = (int)((IV).x & 0xffffu);                  \
        int j1_ = (int)((IV).x >> 16);                      \
        int j2_ = (int)((IV).y & 0xffffu);                  \
        int j3_ = (int)((IV).y >> 16);                      \
        U0 = g2[(size_t)j0_ * 4 + m4];                      \
        U1 = g2[(size_t)j1_ * 4 + m4];                      \
        U2 = g2[(size_t)j2_ * 4 + m4];                      \
        U3 = g2[(size_t)j3_ * 4 + m4];                      \
    } while (0)

    int e = rs[node], e1v = re[node];
    while ((e & 3) && e < e1v) {
        int j = csr_src[e];
        float4 u = g2[(size_t)j * 4 + m4];
        ACC4(u);
        ++e;
    }
    int nb = (e1v - e) >> 2;
    if (nb >= 2) {
        uint2 Ia = *(const uint2*)&csr_src[e];
        uint2 Ib = *(const uint2*)&csr_src[e + 4];
        float4 A0, A1, A2, A3, B0, B1, B2, B3;
        GATH4(Ia, A0, A1, A2, A3);
        GATH4(Ib, B0, B1, B2, B3);
        __builtin_amdgcn_sched_barrier(0);
        int b = 2;
        while (b + 2 <= nb) {
            Ia = *(const uint2*)&csr_src[e + 4 * b];
            ACC4(A0); ACC4(A1); ACC4(A2); ACC4(A3);
            GATH4(Ia, A0, A1, A2, A3);
            __builtin_amdgcn_sched_barrier(0);
            Ib = *(const uint2*)&csr_src[e + 4 * b + 4];
            ACC4(B0); ACC4(B1); ACC4(B2); ACC4(B3);
            GATH4(Ib, B0, B1, B2, B3);
            __builtin_amdgcn_sched_barrier(0);
            b += 2;
        }
        int rem = nb - b;
        ACC4(A0); ACC4(A1); ACC4(A2); ACC4(A3);
        if (rem) {
            Ia = *(const uint2*)&csr_src[e + 4 * b];
            GATH4(Ia, A0, A1, A2, A3);
        }
        ACC4(B0); ACC4(B1); ACC4(B2); ACC4(B3);
        if (rem) { ACC4(A0); ACC4(A1); ACC4(A2); ACC4(A3); }
        e += 4 * nb;
    } else if (nb >= 1) {
        uint2 Iv = *(const uint2*)&csr_src[e];
        float4 U0, U1, U2, U3;
        GATH4(Iv, U0, U1, U2, U3);
        ACC4(U0); ACC4(U1); ACC4(U2); ACC4(U3);
        e += 4;
    }
    while (e < e1v) {
        int j = csr_src[e];
        float4 u = g2[(size_t)j * 4 + m4];
        ACC4(u);
        ++e;
    }
#undef GATH4
#undef ACC4

    float dv = dis[node];
    float4 bb = *(const float4*)&b2[4 * m4];
    float4 lg;
    lg.x = fmaf(dv, acc.x, bb.x);
    lg.y = fmaf(dv, acc.y, bb.y);
    lg.z = fmaf(dv, acc.z, bb.z);
    lg.w = fmaf(dv, acc.w, bb.w);
    ((float4*)out)[(size_t)node * 4 + m4] = lg;

    // softmax over 16 classes = 4 lanes x 4
    float m = fmaxf(fmaxf(lg.x, lg.y), fmaxf(lg.z, lg.w));
    m = fmaxf(m, __shfl_xor(m, 1));
    m = fmaxf(m, __shfl_xor(m, 2));
    float4 ex;
    ex.x = expf(lg.x - m); ex.y = expf(lg.y - m);
    ex.z = expf(lg.z - m); ex.w = expf(lg.w - m);
    float s = (ex.x + ex.y) + (ex.z + ex.w);
    s += __shfl_xor(s, 1);
    s += __shfl_xor(s, 2);
    float inv = 1.0f / s;
    ex.x *= inv; ex.y *= inv; ex.z *= inv; ex.w *= inv;
    ((float4*)out)[(size_t)N_NODES * 4 + (size_t)node * 4 + m4] = ex;
}

// ---------------------------------------------------------------------------

extern "C" void kernel_launch(void* const* d_in, const int* in_sizes, int n_in,
                              void* d_out, int out_size, void* d_ws, size_t ws_size,
                              hipStream_t stream) {
    const float* x  = (const float*)d_in[0];
    const int*   ei = (const int*)d_in[1];
    const float* W1 = (const float*)d_in[2];
    const float* b1 = (const float*)d_in[3];
    const float* W2 = (const float*)d_in[4];
    const float* b2 = (const float*)d_in[5];
    float* out = (float*)d_out;

    char* ws = (char*)d_ws;
    size_t off = 0;
    auto alloc = [&](size_t bytes) -> char* {
        char* p = ws + off;
        off = (off + bytes + 511) & ~(size_t)511;
        return p;
    };
    int*   cursor   = (int*)alloc(256 * CSTR * 4);
    float* dis      = (float*)alloc(N_NODES * 4);
    int*   rs       = (int*)alloc(N_NODES * 4);
    int*   re       = (int*)alloc(N_NODES * 4);
    unsigned short* w1t = (unsigned short*)alloc((size_t)HIDDEN * IN_FEAT * 2);
    unsigned short* csr_src = (unsigned short*)alloc((size_t)NBKT * BCAP * 2);  // holey
    unsigned int* g1 = (unsigned int*)alloc((size_t)N_NODES * 64 * 4);          // slice-major: 4 x [N][16dw]
    float* g2p      = (float*)alloc(4 * (size_t)N_NODES * N_CLASSES * 4);       // per-slice GEMM2 partials
    // sorted edges (196*10240*4 = 8.0MB) alias g1's slab (12.8MB): dead before gemm1.
    unsigned int* sorted = (unsigned int*)g1;
    (void)ws_size; (void)in_sizes; (void)n_in; (void)out_size;

    const int* src = ei;
    const int* dst = ei + N_EDGES;

    hipMemsetAsync(cursor, 0, 256 * CSTR * 4, stream);
    scatter_edges2<<<NCHK, 256, 0, stream>>>(src, dst, cursor, sorted, W1, w1t);
    build_csr2<<<NBKT, 512, 0, stream>>>(sorted, cursor, rs, re, dis, csr_src);

    gemm1_mfma<<<(N_NODES + 63) / 64, 256, 0, stream>>>(x, w1t, dis, g1);
    agg1_sliced<<<NBKT * 16, 256, 0, stream>>>((const uint4*)g1, rs, re, csr_src, dis, b1, W2, g2p);
    g2_reduce<<<(N_NODES * 4 + 255) / 256, 256, 0, stream>>>(g2p, dis);
    agg2_softmax<<<N_NODES / 64 + 1, 256, 0, stream>>>((const float4*)g2p, rs, re, csr_src, dis, b2, out);
}